// Round 1
// baseline (928.314 us; speedup 1.0000x reference)
//
#include <hip/hip_runtime.h>
#include <math.h>

#define TWO_PI_D 6.283185307179586476925286766559
#define SRATE_D  24000.0

// ---------------------------------------------------------------------------
// Basis tables: C[k][n] such that IR_windowed = Mag @ C
// ir = irfft(mag, N); ir = fftshift(ir) * hann(N); analytic collapse:
//   shift by N/2 -> cos(2pi k (n+N/2)/N) = (-1)^k cos(2pi k n /N)
// ---------------------------------------------------------------------------
template<int NMAG, int NIR>
__global__ __launch_bounds__(256) void basis_kernel(float* __restrict__ C)
{
    const int k = blockIdx.x;
    for (int n = threadIdx.x; n < NIR; n += blockDim.x) {
        double hann = 0.5 * (1.0 - cos(TWO_PI_D * (double)n / (double)NIR));
        double w = hann / (double)NIR;
        double v;
        if (k == 0) {
            v = w;
        } else if (k == NMAG - 1) {
            // X_{N/2} * (-1)^(n + N/2) with N/2 odd (511, 79) -> (-1)^(n+1)
            v = (n & 1) ? w : -w;
        } else {
            long m = ((long)k * (long)n) % NIR;
            double c = cos(TWO_PI_D * (double)m / (double)NIR);
            double sgn = (k & 1) ? -1.0 : 1.0;
            v = 2.0 * w * sgn * c;
        }
        C[(size_t)k * NIR + n] = (float)v;
    }
}

// ---------------------------------------------------------------------------
// fp32 tiled GEMM 64x64x16, 256 threads, 4x4 microtile.
// MODE 0: tanh(acc+bias); MODE 1: resid + gelu(acc+bias); MODE 2: acc(+bias)
// Requires M%64==0, K%16==0; N edge-guarded.
// ---------------------------------------------------------------------------
__device__ inline float gelu_f(float x) {
    float x3 = x * x * x;
    float t = tanhf(0.7978845608028654f * (x + 0.044715f * x3));
    return 0.5f * x * (1.0f + t);
}

template<int MODE>
__global__ __launch_bounds__(256) void gemm_kernel(
    const float* __restrict__ A, const float* __restrict__ Bm,
    const float* __restrict__ bias, const float* __restrict__ resid,
    float* __restrict__ C, int M, int N, int K)
{
    __shared__ float As[16][68];
    __shared__ float Bs[16][68];
    const int tid = threadIdx.x;
    const int tx = tid & 15, ty = tid >> 4;
    const int m0 = blockIdx.x * 64;
    const int n0 = blockIdx.y * 64;
    const int ar  = tid >> 2;
    const int ac4 = (tid & 3) << 2;
    const int bk  = tid >> 4;
    const int bn4 = (tid & 15) << 2;
    float acc[4][4] = {};
    for (int k0 = 0; k0 < K; k0 += 16) {
        float4 av = *(const float4*)(A + (size_t)(m0 + ar) * K + k0 + ac4);
        As[ac4 + 0][ar] = av.x;
        As[ac4 + 1][ar] = av.y;
        As[ac4 + 2][ar] = av.z;
        As[ac4 + 3][ar] = av.w;
        const float* Bp = Bm + (size_t)(k0 + bk) * N + n0 + bn4;
        #pragma unroll
        for (int i = 0; i < 4; i++)
            Bs[bk][bn4 + i] = (n0 + bn4 + i < N) ? Bp[i] : 0.0f;
        __syncthreads();
        #pragma unroll
        for (int kk = 0; kk < 16; kk++) {
            float4 a4 = *(const float4*)&As[kk][ty << 2];
            float4 b4 = *(const float4*)&Bs[kk][tx << 2];
            float a[4] = {a4.x, a4.y, a4.z, a4.w};
            float b[4] = {b4.x, b4.y, b4.z, b4.w};
            #pragma unroll
            for (int i = 0; i < 4; i++)
                #pragma unroll
                for (int j = 0; j < 4; j++)
                    acc[i][j] = fmaf(a[i], b[j], acc[i][j]);
        }
        __syncthreads();
    }
    #pragma unroll
    for (int i = 0; i < 4; i++) {
        int m = m0 + (ty << 2) + i;
        #pragma unroll
        for (int j = 0; j < 4; j++) {
            int n = n0 + (tx << 2) + j;
            if (n < N) {
                float v = acc[i][j];
                if (bias) v += bias[n];
                if (MODE == 0) v = tanhf(v);
                else if (MODE == 1) v = resid[(size_t)m * N + n] + gelu_f(v);
                C[(size_t)m * N + n] = v;
            }
        }
    }
}

// ---------------------------------------------------------------------------
// Split MLP output into f0 / src_param / noise_param
// ---------------------------------------------------------------------------
__global__ __launch_bounds__(256) void transform_kernel(
    const float* __restrict__ O, float* __restrict__ f0w, float* __restrict__ f0out,
    float* __restrict__ SP, float* __restrict__ NP)
{
    int idx = blockIdx.x * 256 + threadIdx.x;
    if (idx >= 8000 * 593) return;
    int row = idx / 593;
    int col = idx - row * 593;
    float v = O[idx];
    float s = 1.0f / (1.0f + expf(-v));
    if (col == 0) {
        float f0 = 80.0f * powf(12.5f, s);   // 80 * (1000/80)^sigmoid
        if (f0 < 80.0f) f0 = 0.0f;
        f0w[row]   = f0;
        f0out[row] = f0;
    } else if (col < 513) {
        SP[(size_t)row * 512 + (col - 1)]  = 2.0f * powf(s, 2.3025851f) + 1e-7f;
    } else {
        NP[(size_t)row * 80 + (col - 513)] = 2.0f * powf(s, 2.3025851f) + 1e-7f;
    }
}

// ---------------------------------------------------------------------------
// Per-batch fp64 frame-level scan of pitch sums.
// Frame sum: sum_{j=0..239} [f0c(1-j/240) + f0n(j/240)] = 120.5 f0c + 119.5 f0n
// ---------------------------------------------------------------------------
__global__ void scan_kernel(const float* __restrict__ f0w, const float* __restrict__ iphase,
                            double* __restrict__ base, float* __restrict__ fph)
{
    int b = threadIdx.x;
    if (b >= 8) return;
    const float* f0 = f0w + b * 1000;
    double acc = 0.0;
    for (int f = 0; f < 1000; f++) {
        base[b * 1000 + f] = acc;
        double c  = (double)f0[f];
        double nx = (double)f0[(f < 999) ? (f + 1) : 999];
        acc += 120.5 * c + 119.5 * nx;
    }
    double u  = acc / SRATE_D;
    double ph = TWO_PI_D * u + (double)iphase[b];
    fph[b] = (float)fmod(ph, TWO_PI_D);
}

// ---------------------------------------------------------------------------
// Sawtooth (fp64 phase) + threefry2x32 noise (bit-exact jax.random.uniform)
// ---------------------------------------------------------------------------
__device__ inline unsigned rotl32(unsigned x, int d) { return (x << d) | (x >> (32 - d)); }

__global__ __launch_bounds__(256) void saw_noise_kernel(
    const float* __restrict__ f0w, const double* __restrict__ base,
    const float* __restrict__ iphase, float* __restrict__ saw, float* __restrict__ nz)
{
    int idx = blockIdx.x * 256 + threadIdx.x;
    if (idx >= 8 * 240000) return;
    int b = idx / 240000;
    int t = idx - b * 240000;
    int f = t / 240;
    int r = t - f * 240;
    double c  = (double)f0w[b * 1000 + f];
    double nx = (double)f0w[b * 1000 + ((f < 999) ? (f + 1) : 999)];
    double rr = (double)r;
    double Bc = rr * (rr + 1.0) * (1.0 / 480.0);   // sum j/240, j=0..r
    double Ac = (rr + 1.0) - Bc;                   // sum (1-j/240)
    double cum = base[b * 1000 + f] + Ac * c + Bc * nx;
    double u  = cum / SRATE_D + (double)iphase[b] / TWO_PI_D;
    double fr = u - floor(u);
    saw[idx] = (float)(2.0 * fr - 1.0);

    // threefry2x32, key = (0, 123); count split: (i, i+N/2)
    const unsigned n2 = 960000u;
    unsigned mi = (unsigned)idx;
    unsigned i0 = (mi < n2) ? mi : (mi - n2);
    unsigned x0 = i0, x1 = i0 + n2;
    const unsigned ks0 = 0u, ks1 = 123u, ks2 = 0x1BD11BDAu ^ 0u ^ 123u;
    x0 += ks0; x1 += ks1;
#define TF_R(rot) { x0 += x1; x1 = rotl32(x1, rot); x1 ^= x0; }
    TF_R(13) TF_R(15) TF_R(26) TF_R(6)
    x0 += ks1; x1 += ks2 + 1u;
    TF_R(17) TF_R(29) TF_R(16) TF_R(24)
    x0 += ks2; x1 += ks0 + 2u;
    TF_R(13) TF_R(15) TF_R(26) TF_R(6)
    x0 += ks0; x1 += ks1 + 3u;
    TF_R(17) TF_R(29) TF_R(16) TF_R(24)
    x0 += ks1; x1 += ks2 + 4u;
    TF_R(13) TF_R(15) TF_R(26) TF_R(6)
    x0 += ks2; x1 += ks0 + 5u;
#undef TF_R
    unsigned bits = (mi < n2) ? x0 : x1;
    float uf = __uint_as_float((bits >> 9) | 0x3f800000u) - 1.0f;
    nz[idx] = uf * 2.0f - 1.0f;
}

// ---------------------------------------------------------------------------
// Time-varying FIR conv + overlap-add + 'same' slice, gather form:
//   out[t] = sum_{tau = t+START-IRL+1 .. t+START} audio[tau] * IR[tau/240][t+START-tau]
// 1024 outputs/block, 4 consecutive outputs/thread, audio+IR staged in LDS.
// ---------------------------------------------------------------------------
template<int IRL, int START, int NFMAX>
__global__ __launch_bounds__(256) void tvconv_kernel(
    const float* __restrict__ audio, const float* __restrict__ IR,
    float* __restrict__ out)
{
    constexpr int T = 240000;
    constexpr int NF = 1000;
    constexpr int OPB = 1024;
    constexpr int HALO = OPB + IRL - 1;
    constexpr int S_TOTAL = (IRL + 6) & ~3;   // multiple of 4, >= IRL+3
    __shared__ float audio_s[HALO + 8];
    __shared__ float ir_s[NFMAX * IRL + 16];
    const int b  = blockIdx.y;
    const int t0 = blockIdx.x * OPB;
    const int tau_lo = t0 + START - (IRL - 1);
    const int tau_hi = t0 + OPB - 1 + START;
    const int f_lo = max(0, tau_lo) / 240;
    const int f_hi = min(tau_hi, T - 1) / 240;
    const int nf   = f_hi - f_lo + 1;
    const int nfm1 = nf - 1;
    const int tid  = threadIdx.x;

    for (int i = tid; i < HALO + 8; i += 256) {
        int tau = tau_lo + i;
        audio_s[i] = (tau >= 0 && tau < T) ? audio[(size_t)b * T + tau] : 0.0f;
    }
    for (int i = tid; i < nf * IRL; i += 256) {
        int fl = i / IRL;
        int d  = i - fl * IRL;
        ir_s[8 + i] = IR[((size_t)b * NF + f_lo + fl) * IRL + d];
    }
    __syncthreads();

    const int tb = t0 + (tid << 2);
    float acc0 = 0.f, acc1 = 0.f, acc2 = 0.f, acc3 = 0.f;
    const int tau_start = tb + START - (IRL - 1);
    int tpos = tau_start + 720;                 // make positive for div/mod
    int fq   = (int)((unsigned)tpos / 240u);
    int cnt  = tpos - fq * 240;
    int frel = fq - 3 - f_lo;                   // frame rel to f_lo (may be <0)
    const int abase = tid << 2;

    #pragma unroll 1
    for (int s4 = 0; s4 < S_TOTAL; s4 += 4) {
        float4 a4 = *(const float4*)&audio_s[abase + s4];
        #pragma unroll
        for (int k = 0; k < 4; k++) {
            int s = s4 + k;
            float av = (k == 0) ? a4.x : (k == 1) ? a4.y : (k == 2) ? a4.z : a4.w;
            int d0 = (IRL - 1) - s;
            int floc = min(max(frel, 0), nfm1);
            const float* irp = &ir_s[8 + floc * IRL + d0];
            acc0 = ((unsigned)(d0 + 0) < (unsigned)IRL) ? fmaf(av, irp[0], acc0) : acc0;
            acc1 = ((unsigned)(d0 + 1) < (unsigned)IRL) ? fmaf(av, irp[1], acc1) : acc1;
            acc2 = ((unsigned)(d0 + 2) < (unsigned)IRL) ? fmaf(av, irp[2], acc2) : acc2;
            acc3 = ((unsigned)(d0 + 3) < (unsigned)IRL) ? fmaf(av, irp[3], acc3) : acc3;
            cnt++;
            if (cnt == 240) { cnt = 0; frel++; }
        }
    }
    const size_t ob = (size_t)b * T;
    if (tb + 0 < T) out[ob + tb + 0] = acc0;
    if (tb + 1 < T) out[ob + tb + 1] = acc1;
    if (tb + 2 < T) out[ob + tb + 2] = acc2;
    if (tb + 3 < T) out[ob + tb + 3] = acc3;
}

__global__ __launch_bounds__(256) void add_kernel(
    const float* __restrict__ a, const float* __restrict__ c,
    float* __restrict__ o, int n)
{
    int i = blockIdx.x * 256 + threadIdx.x;
    if (i < n) o[i] = a[i] + c[i];
}

// ---------------------------------------------------------------------------
extern "C" void kernel_launch(void* const* d_in, const int* in_sizes, int n_in,
                              void* d_out, int out_size, void* d_ws, size_t ws_size,
                              hipStream_t stream)
{
    (void)in_sizes; (void)n_in; (void)out_size; (void)ws_size;
    const float* mel    = (const float*)d_in[0];
    const float* iphase = (const float*)d_in[1];
    const float* W_in   = (const float*)d_in[2];
    const float* b_in   = (const float*)d_in[3];
    const float* W1     = (const float*)d_in[4];
    const float* b1     = (const float*)d_in[5];
    const float* W2     = (const float*)d_in[6];
    const float* b2     = (const float*)d_in[7];
    const float* W_out  = (const float*)d_in[8];
    const float* b_out  = (const float*)d_in[9];
    float* ws = (float*)d_ws;

    // workspace layout (floats)
    float*  Ch   = ws;                       // 512*1022   = 523264
    float*  Cn   = Ch + 523264;              // 80*158     = 12640
    float*  SP   = Cn + 12640;               // 8000*512   = 4096000
    float*  NP   = SP + 4096000;             // 8000*80    = 640000
    float*  f0w  = NP + 640000;              // 8000
    double* base = (double*)(f0w + 8000);    // 8000 doubles (16000 floats)
    float*  saw  = f0w + 8000 + 16000;       // 1920000
    float*  nz   = saw + 1920000;            // 1920000
    float*  BA   = nz + 1920000;             // 2048000  (H1 then H3)
    float*  BB   = BA + 2048000;             // 2048000  (H2)
    float*  BO   = BB + 2048000;             // 4744000  (O)
    float*  IRh  = BA;                       // 8176000  (reuses BA+BB+BO head)
    float*  IRn  = BO + 4744000;             // 1264000

    float* out       = (float*)d_out;
    float* sig_out   = out;                  // [8,240000]
    float* f0_out    = out + 1920000;        // [8,1000,1]
    float* fph_out   = out + 1928000;        // [8,1,1]
    float* harm_out  = out + 1928008;        // [8,240000]
    float* noise_out = out + 3848008;        // [8,240000]

    basis_kernel<512, 1022><<<512, 256, 0, stream>>>(Ch);
    basis_kernel<80, 158><<<80, 256, 0, stream>>>(Cn);

    // MLP: h=tanh(mel@W_in+b); h+=gelu(h@W1+b1); h+=gelu(h@W2+b2); o=h@W_out+b
    gemm_kernel<0><<<dim3(125, 4),  256, 0, stream>>>(mel, W_in, b_in, nullptr, BA, 8000, 256, 80);
    gemm_kernel<1><<<dim3(125, 4),  256, 0, stream>>>(BA,  W1,   b1,   BA,      BB, 8000, 256, 256);
    gemm_kernel<1><<<dim3(125, 4),  256, 0, stream>>>(BB,  W2,   b2,   BB,      BA, 8000, 256, 256);
    gemm_kernel<2><<<dim3(125, 10), 256, 0, stream>>>(BA,  W_out, b_out, nullptr, BO, 8000, 593, 256);

    transform_kernel<<<(8000 * 593 + 255) / 256, 256, 0, stream>>>(BO, f0w, f0_out, SP, NP);
    scan_kernel<<<1, 64, 0, stream>>>(f0w, iphase, base, fph_out);
    saw_noise_kernel<<<(1920000 + 255) / 256, 256, 0, stream>>>(f0w, base, iphase, saw, nz);

    // IR = Mag @ C  (windowed, shifted irfft)
    gemm_kernel<2><<<dim3(125, 16), 256, 0, stream>>>(SP, Ch, nullptr, nullptr, IRh, 8000, 1022, 512);
    gemm_kernel<2><<<dim3(125, 3),  256, 0, stream>>>(NP, Cn, nullptr, nullptr, IRn, 8000, 158, 80);

    // time-varying conv + OLA + 'same' slice
    tvconv_kernel<1022, 509, 10><<<dim3(235, 8), 256, 0, stream>>>(saw, IRh, harm_out);
    tvconv_kernel<158, 77, 6><<<dim3(235, 8), 256, 0, stream>>>(nz, IRn, noise_out);

    add_kernel<<<(1920000 + 255) / 256, 256, 0, stream>>>(harm_out, noise_out, sig_out, 1920000);
}

// Round 2
// 651.375 us; speedup vs baseline: 1.4252x; 1.4252x over previous
//
#include <hip/hip_runtime.h>
#include <math.h>

#define TWO_PI_D 6.283185307179586476925286766559
#define SRATE_D  24000.0

// ---------------------------------------------------------------------------
// Basis tables: C[k][n] such that IR_windowed = Mag @ C
// ---------------------------------------------------------------------------
template<int NMAG, int NIR>
__global__ __launch_bounds__(256) void basis_kernel(float* __restrict__ C)
{
    const int k = blockIdx.x;
    for (int n = threadIdx.x; n < NIR; n += blockDim.x) {
        double hann = 0.5 * (1.0 - cos(TWO_PI_D * (double)n / (double)NIR));
        double w = hann / (double)NIR;
        double v;
        if (k == 0) {
            v = w;
        } else if (k == NMAG - 1) {
            v = (n & 1) ? w : -w;
        } else {
            long m = ((long)k * (long)n) % NIR;
            double c = cos(TWO_PI_D * (double)m / (double)NIR);
            double sgn = (k & 1) ? -1.0 : 1.0;
            v = 2.0 * w * sgn * c;
        }
        C[(size_t)k * NIR + n] = (float)v;
    }
}

// ---------------------------------------------------------------------------
// fp32 tiled GEMM 64x64x16, 256 threads, 4x4 microtile.
// ---------------------------------------------------------------------------
__device__ inline float gelu_f(float x) {
    float x3 = x * x * x;
    float t = tanhf(0.7978845608028654f * (x + 0.044715f * x3));
    return 0.5f * x * (1.0f + t);
}

template<int MODE>
__global__ __launch_bounds__(256) void gemm_kernel(
    const float* __restrict__ A, const float* __restrict__ Bm,
    const float* __restrict__ bias, const float* __restrict__ resid,
    float* __restrict__ C, int M, int N, int K)
{
    __shared__ float As[16][68];
    __shared__ float Bs[16][68];
    const int tid = threadIdx.x;
    const int tx = tid & 15, ty = tid >> 4;
    const int m0 = blockIdx.x * 64;
    const int n0 = blockIdx.y * 64;
    const int ar  = tid >> 2;
    const int ac4 = (tid & 3) << 2;
    const int bk  = tid >> 4;
    const int bn4 = (tid & 15) << 2;
    float acc[4][4] = {};
    for (int k0 = 0; k0 < K; k0 += 16) {
        float4 av = *(const float4*)(A + (size_t)(m0 + ar) * K + k0 + ac4);
        As[ac4 + 0][ar] = av.x;
        As[ac4 + 1][ar] = av.y;
        As[ac4 + 2][ar] = av.z;
        As[ac4 + 3][ar] = av.w;
        const float* Bp = Bm + (size_t)(k0 + bk) * N + n0 + bn4;
        #pragma unroll
        for (int i = 0; i < 4; i++)
            Bs[bk][bn4 + i] = (n0 + bn4 + i < N) ? Bp[i] : 0.0f;
        __syncthreads();
        #pragma unroll
        for (int kk = 0; kk < 16; kk++) {
            float4 a4 = *(const float4*)&As[kk][ty << 2];
            float4 b4 = *(const float4*)&Bs[kk][tx << 2];
            float a[4] = {a4.x, a4.y, a4.z, a4.w};
            float b[4] = {b4.x, b4.y, b4.z, b4.w};
            #pragma unroll
            for (int i = 0; i < 4; i++)
                #pragma unroll
                for (int j = 0; j < 4; j++)
                    acc[i][j] = fmaf(a[i], b[j], acc[i][j]);
        }
        __syncthreads();
    }
    #pragma unroll
    for (int i = 0; i < 4; i++) {
        int m = m0 + (ty << 2) + i;
        #pragma unroll
        for (int j = 0; j < 4; j++) {
            int n = n0 + (tx << 2) + j;
            if (n < N) {
                float v = acc[i][j];
                if (bias) v += bias[n];
                if (MODE == 0) v = tanhf(v);
                else if (MODE == 1) v = resid[(size_t)m * N + n] + gelu_f(v);
                C[(size_t)m * N + n] = v;
            }
        }
    }
}

// ---------------------------------------------------------------------------
// Split MLP output into f0 / src_param / noise_param
// ---------------------------------------------------------------------------
__global__ __launch_bounds__(256) void transform_kernel(
    const float* __restrict__ O, float* __restrict__ f0w, float* __restrict__ f0out,
    float* __restrict__ SP, float* __restrict__ NP)
{
    int idx = blockIdx.x * 256 + threadIdx.x;
    if (idx >= 8000 * 593) return;
    int row = idx / 593;
    int col = idx - row * 593;
    float v = O[idx];
    float s = 1.0f / (1.0f + expf(-v));
    if (col == 0) {
        float f0 = 80.0f * powf(12.5f, s);
        if (f0 < 80.0f) f0 = 0.0f;
        f0w[row]   = f0;
        f0out[row] = f0;
    } else if (col < 513) {
        SP[(size_t)row * 512 + (col - 1)]  = 2.0f * powf(s, 2.3025851f) + 1e-7f;
    } else {
        NP[(size_t)row * 80 + (col - 513)] = 2.0f * powf(s, 2.3025851f) + 1e-7f;
    }
}

// ---------------------------------------------------------------------------
// Per-batch fp64 frame-level scan of pitch sums.
// ---------------------------------------------------------------------------
__global__ void scan_kernel(const float* __restrict__ f0w, const float* __restrict__ iphase,
                            double* __restrict__ base, float* __restrict__ fph)
{
    int b = threadIdx.x;
    if (b >= 8) return;
    const float* f0 = f0w + b * 1000;
    double acc = 0.0;
    for (int f = 0; f < 1000; f++) {
        base[b * 1000 + f] = acc;
        double c  = (double)f0[f];
        double nx = (double)f0[(f < 999) ? (f + 1) : 999];
        acc += 120.5 * c + 119.5 * nx;
    }
    double u  = acc / SRATE_D;
    double ph = TWO_PI_D * u + (double)iphase[b];
    fph[b] = (float)fmod(ph, TWO_PI_D);
}

// ---------------------------------------------------------------------------
// Sawtooth (fp64 phase) + threefry2x32 noise (bit-exact jax.random.uniform)
// ---------------------------------------------------------------------------
__device__ inline unsigned rotl32(unsigned x, int d) { return (x << d) | (x >> (32 - d)); }

__global__ __launch_bounds__(256) void saw_noise_kernel(
    const float* __restrict__ f0w, const double* __restrict__ base,
    const float* __restrict__ iphase, float* __restrict__ saw, float* __restrict__ nz)
{
    int idx = blockIdx.x * 256 + threadIdx.x;
    if (idx >= 8 * 240000) return;
    int b = idx / 240000;
    int t = idx - b * 240000;
    int f = t / 240;
    int r = t - f * 240;
    double c  = (double)f0w[b * 1000 + f];
    double nx = (double)f0w[b * 1000 + ((f < 999) ? (f + 1) : 999)];
    double rr = (double)r;
    double Bc = rr * (rr + 1.0) * (1.0 / 480.0);
    double Ac = (rr + 1.0) - Bc;
    double cum = base[b * 1000 + f] + Ac * c + Bc * nx;
    double u  = cum / SRATE_D + (double)iphase[b] / TWO_PI_D;
    double fr = u - floor(u);
    saw[idx] = (float)(2.0 * fr - 1.0);

    const unsigned n2 = 960000u;
    unsigned mi = (unsigned)idx;
    unsigned i0 = (mi < n2) ? mi : (mi - n2);
    unsigned x0 = i0, x1 = i0 + n2;
    const unsigned ks0 = 0u, ks1 = 123u, ks2 = 0x1BD11BDAu ^ 0u ^ 123u;
    x0 += ks0; x1 += ks1;
#define TF_R(rot) { x0 += x1; x1 = rotl32(x1, rot); x1 ^= x0; }
    TF_R(13) TF_R(15) TF_R(26) TF_R(6)
    x0 += ks1; x1 += ks2 + 1u;
    TF_R(17) TF_R(29) TF_R(16) TF_R(24)
    x0 += ks2; x1 += ks0 + 2u;
    TF_R(13) TF_R(15) TF_R(26) TF_R(6)
    x0 += ks0; x1 += ks1 + 3u;
    TF_R(17) TF_R(29) TF_R(16) TF_R(24)
    x0 += ks1; x1 += ks2 + 4u;
    TF_R(13) TF_R(15) TF_R(26) TF_R(6)
    x0 += ks2; x1 += ks0 + 5u;
#undef TF_R
    unsigned bits = (mi < n2) ? x0 : x1;
    float uf = __uint_as_float((bits >> 9) | 0x3f800000u) - 1.0f;
    nz[idx] = uf * 2.0f - 1.0f;
}

// ---------------------------------------------------------------------------
// Per-frame linear convolution, harmonic: y_f[j] = sum_i audio_f[i]*IR_f[j-i]
// j in [0,1261); uniform IR row per block -> no frame-boundary logic.
// 320 threads * 4 outputs = 1280 slots. Rolling 8-reg IR window, b128 reads.
// ---------------------------------------------------------------------------
#define CONV_GROUP(u4) \
    a0 = fmaf(u4.x, Whi.x, a0); a1 = fmaf(u4.x, Whi.y, a1); a2 = fmaf(u4.x, Whi.z, a2); a3 = fmaf(u4.x, Whi.w, a3); \
    a0 = fmaf(u4.y, Wlo.w, a0); a1 = fmaf(u4.y, Whi.x, a1); a2 = fmaf(u4.y, Whi.y, a2); a3 = fmaf(u4.y, Whi.z, a3); \
    a0 = fmaf(u4.z, Wlo.z, a0); a1 = fmaf(u4.z, Wlo.w, a1); a2 = fmaf(u4.z, Whi.x, a2); a3 = fmaf(u4.z, Whi.y, a3); \
    a0 = fmaf(u4.w, Wlo.y, a0); a1 = fmaf(u4.w, Wlo.z, a1); a2 = fmaf(u4.w, Wlo.w, a2); a3 = fmaf(u4.w, Whi.x, a3);

__global__ __launch_bounds__(320) void frameconv_h(
    const float* __restrict__ audio, const float* __restrict__ IR,
    float* __restrict__ Y, int fstart, int nfc)
{
    __shared__ __align__(16) float u_s[240];
    __shared__ __align__(16) float w_s[1520];
    const int fl = blockIdx.x;
    const int b  = blockIdx.y;
    const int f  = fstart + fl;
    const int tid = threadIdx.x;
    for (int i = tid; i < 240; i += 320) {
        u_s[i] = audio[(size_t)b * 240000 + (size_t)f * 240 + i];
        w_s[i] = 0.0f;
    }
    for (int i = tid; i < 258; i += 320) w_s[1262 + i] = 0.0f;
    const float* irow = IR + ((size_t)b * 1000 + f) * 1022;
    for (int i = tid; i < 1022; i += 320) w_s[240 + i] = irow[i];
    __syncthreads();

    const int j0 = tid << 2;
    int base = 240 + j0 - 4;
    float4 Wlo = *(const float4*)&w_s[base];
    float4 Whi = *(const float4*)&w_s[base + 4];
    float a0 = 0.f, a1 = 0.f, a2 = 0.f, a3 = 0.f;
    #pragma unroll 4
    for (int t = 0; t < 236; t += 4) {
        float4 u4 = *(const float4*)&u_s[t];
        CONV_GROUP(u4)
        Whi = Wlo;
        base -= 4;
        Wlo = *(const float4*)&w_s[base];
    }
    {
        float4 u4 = *(const float4*)&u_s[236];
        CONV_GROUP(u4)
    }
    float4 r; r.x = a0; r.y = a1; r.z = a2; r.w = a3;
    *(float4*)&Y[((size_t)b * nfc + fl) * 1280 + j0] = r;
}

// ---------------------------------------------------------------------------
// Per-frame conv, noise: roles swapped (iterate IR (158->160 padded), window
// over zero-padded audio frame). j in [0,397). 128 threads, 100 store.
// ---------------------------------------------------------------------------
__global__ __launch_bounds__(128) void frameconv_n(
    const float* __restrict__ audio, const float* __restrict__ IR,
    float* __restrict__ Y, int fstart, int nfc)
{
    __shared__ __align__(16) float u_s[160];
    __shared__ __align__(16) float w_s[560];
    const int fl = blockIdx.x;
    const int b  = blockIdx.y;
    const int f  = fstart + fl;
    const int tid = threadIdx.x;
    const float* irow = IR + ((size_t)b * 1000 + f) * 158;
    for (int i = tid; i < 160; i += 128) {
        u_s[i] = (i < 158) ? irow[i] : 0.0f;
        w_s[i] = 0.0f;
        w_s[400 + i] = 0.0f;
    }
    for (int i = tid; i < 240; i += 128)
        w_s[160 + i] = audio[(size_t)b * 240000 + (size_t)f * 240 + i];
    __syncthreads();

    const int j0 = tid << 2;
    if (j0 >= 400) return;
    int base = 160 + j0 - 4;
    float4 Wlo = *(const float4*)&w_s[base];
    float4 Whi = *(const float4*)&w_s[base + 4];
    float a0 = 0.f, a1 = 0.f, a2 = 0.f, a3 = 0.f;
    #pragma unroll 4
    for (int t = 0; t < 156; t += 4) {
        float4 u4 = *(const float4*)&u_s[t];
        CONV_GROUP(u4)
        Whi = Wlo;
        base -= 4;
        Wlo = *(const float4*)&w_s[base];
    }
    {
        float4 u4 = *(const float4*)&u_s[156];
        CONV_GROUP(u4)
    }
    float4 r; r.x = a0; r.y = a1; r.z = a2; r.w = a3;
    *(float4*)&Y[((size_t)b * nfc + fl) * 400 + j0] = r;
}

// ---------------------------------------------------------------------------
// Overlap-add + 'same' slice + harm/noise/signal writes for one t-chunk.
// out[t] = sum_f Yh[f][t+509-240f] ; noise analog with start 77.
// ---------------------------------------------------------------------------
__global__ __launch_bounds__(256) void combine_kernel(
    const float* __restrict__ Yh, const float* __restrict__ Yn,
    int fstart, int nfc, int t0c, int tcnt,
    float* __restrict__ sig, float* __restrict__ harm, float* __restrict__ noise)
{
    int idx = blockIdx.x * 256 + threadIdx.x;
    if (idx >= tcnt) return;
    const int b = blockIdx.y;
    const int t = t0c + idx;
    float hsum = 0.0f;
    const int fhi = (t + 509) / 240;
    #pragma unroll
    for (int q = 0; q < 6; q++) {
        int f = fhi - q;
        int j = t + 509 - 240 * f;
        if (f >= 0 && f < 1000 && j < 1261)
            hsum += Yh[((size_t)b * nfc + (f - fstart)) * 1280 + j];
    }
    float nsum = 0.0f;
    const int ghi = (t + 77) / 240;
    #pragma unroll
    for (int q = 0; q < 2; q++) {
        int f = ghi - q;
        int j = t + 77 - 240 * f;
        if (f >= 0 && f < 1000 && j < 397)
            nsum += Yn[((size_t)b * nfc + (f - fstart)) * 400 + j];
    }
    size_t o = (size_t)b * 240000 + t;
    harm[o]  = hsum;
    noise[o] = nsum;
    sig[o]   = hsum + nsum;
}

// ---------------------------------------------------------------------------
extern "C" void kernel_launch(void* const* d_in, const int* in_sizes, int n_in,
                              void* d_out, int out_size, void* d_ws, size_t ws_size,
                              hipStream_t stream)
{
    (void)in_sizes; (void)n_in; (void)out_size; (void)ws_size;
    const float* mel    = (const float*)d_in[0];
    const float* iphase = (const float*)d_in[1];
    const float* W_in   = (const float*)d_in[2];
    const float* b_in   = (const float*)d_in[3];
    const float* W1     = (const float*)d_in[4];
    const float* b1     = (const float*)d_in[5];
    const float* W2     = (const float*)d_in[6];
    const float* b2     = (const float*)d_in[7];
    const float* W_out  = (const float*)d_in[8];
    const float* b_out  = (const float*)d_in[9];
    float* ws = (float*)d_ws;

    // workspace layout (floats) — peak 19,239,904 floats (same as round 1)
    float*  Ch   = ws;                       // 523,264
    float*  Cn   = Ch + 523264;              // 12,640
    float*  SP   = Cn + 12640;               // 4,096,000
    float*  NP   = SP + 4096000;             // 640,000
    float*  f0w  = NP + 640000;              // 8,000
    double* base = (double*)(f0w + 8000);    // 8,000 doubles
    float*  saw  = f0w + 8000 + 16000;       // 1,920,000
    float*  nz   = saw + 1920000;            // 1,920,000
    float*  BA   = nz + 1920000;             // 2,048,000
    float*  BB   = BA + 2048000;             // 2,048,000
    float*  BO   = BB + 2048000;             // 4,744,000
    float*  IRn  = BO + 4744000;             // 1,264,000
    float*  IRh  = BA;                       // 8,176,000 (aliases BA+BB+BO head; all dead)
    float*  YhC  = ws;                       // 2,621,440 (aliases Ch/Cn/SP head; dead at conv)
    float*  YnC  = ws + 2621440;             // 819,200   (aliases SP; dead at conv)

    float* out       = (float*)d_out;
    float* sig_out   = out;                  // [8,240000]
    float* f0_out    = out + 1920000;        // [8,1000,1]
    float* fph_out   = out + 1928000;        // [8,1,1]
    float* harm_out  = out + 1928008;        // [8,240000]
    float* noise_out = out + 3848008;        // [8,240000]

    basis_kernel<512, 1022><<<512, 256, 0, stream>>>(Ch);
    basis_kernel<80, 158><<<80, 256, 0, stream>>>(Cn);

    gemm_kernel<0><<<dim3(125, 4),  256, 0, stream>>>(mel, W_in, b_in, nullptr, BA, 8000, 256, 80);
    gemm_kernel<1><<<dim3(125, 4),  256, 0, stream>>>(BA,  W1,   b1,   BA,      BB, 8000, 256, 256);
    gemm_kernel<1><<<dim3(125, 4),  256, 0, stream>>>(BB,  W2,   b2,   BB,      BA, 8000, 256, 256);
    gemm_kernel<2><<<dim3(125, 10), 256, 0, stream>>>(BA,  W_out, b_out, nullptr, BO, 8000, 593, 256);

    transform_kernel<<<(8000 * 593 + 255) / 256, 256, 0, stream>>>(BO, f0w, f0_out, SP, NP);
    scan_kernel<<<1, 64, 0, stream>>>(f0w, iphase, base, fph_out);
    saw_noise_kernel<<<(1920000 + 255) / 256, 256, 0, stream>>>(f0w, base, iphase, saw, nz);

    // IR = Mag @ C
    gemm_kernel<2><<<dim3(125, 16), 256, 0, stream>>>(SP, Ch, nullptr, nullptr, IRh, 8000, 1022, 512);
    gemm_kernel<2><<<dim3(125, 3),  256, 0, stream>>>(NP, Cn, nullptr, nullptr, IRn, 8000, 158, 80);

    // chunked per-frame conv + overlap-add (4 chunks of 250 output-frames)
    for (int c = 0; c < 4; c++) {
        int fs   = (c == 0) ? 0 : (250 * c - 3);
        int fe   = (c == 3) ? 1000 : (250 * (c + 1) + 3);
        int nfc  = fe - fs;                          // 253,256,256,253
        int t0c  = 250 * 240 * c;
        int tcnt = 60000;
        frameconv_h<<<dim3(nfc, 8), 320, 0, stream>>>(saw, IRh, YhC, fs, nfc);
        frameconv_n<<<dim3(nfc, 8), 128, 0, stream>>>(nz,  IRn, YnC, fs, nfc);
        combine_kernel<<<dim3((tcnt + 255) / 256, 8), 256, 0, stream>>>(
            YhC, YnC, fs, nfc, t0c, tcnt, sig_out, harm_out, noise_out);
    }
}

// Round 3
// 404.956 us; speedup vs baseline: 2.2924x; 1.6085x over previous
//
#include <hip/hip_runtime.h>
#include <hip/hip_bf16.h>
#include <math.h>

#define TWO_PI_D 6.283185307179586476925286766559
#define TWO_PI_F 6.28318530718f

typedef short bf16x8 __attribute__((ext_vector_type(8)));
typedef float f32x4 __attribute__((ext_vector_type(4)));

// ---------------------------------------------------------------------------
// Harmonic basis, bf16, TRANSPOSED + padded: Ct[n][k], n<1024 (1022 valid), k<512
// C[k][n] = hann(n)/N * {1 | 2(-1)^k cos(2pi k n/N) | (-1)^(n+1)}
// ---------------------------------------------------------------------------
__global__ __launch_bounds__(256) void basis_h_bf16_t(__hip_bfloat16* __restrict__ Ct)
{
    const int n = blockIdx.x;            // 0..1023
    for (int k = threadIdx.x; k < 512; k += 256) {
        float v = 0.0f;
        if (n < 1022) {
            float hann = 0.5f * (1.0f - cosf(TWO_PI_F * (float)n / 1022.0f));
            float w = hann * (1.0f / 1022.0f);
            if (k == 0) v = w;
            else if (k == 511) v = (n & 1) ? w : -w;
            else {
                int m = (k * n) % 1022;
                float c = cosf(TWO_PI_F * (float)m / 1022.0f);
                v = 2.0f * w * ((k & 1) ? -c : c);
            }
        }
        Ct[(size_t)n * 512 + k] = __float2bfloat16(v);
    }
}

// noise basis, fp32 (kept on fp32 path): C[k][n], k<80, n<158
template<int NMAG, int NIR>
__global__ __launch_bounds__(256) void basis_kernel(float* __restrict__ C)
{
    const int k = blockIdx.x;
    for (int n = threadIdx.x; n < NIR; n += blockDim.x) {
        double hann = 0.5 * (1.0 - cos(TWO_PI_D * (double)n / (double)NIR));
        double w = hann / (double)NIR;
        double v;
        if (k == 0) v = w;
        else if (k == NMAG - 1) v = (n & 1) ? w : -w;
        else {
            long m = ((long)k * (long)n) % NIR;
            double c = cos(TWO_PI_D * (double)m / (double)NIR);
            v = 2.0 * w * ((k & 1) ? -c : c);
        }
        C[(size_t)k * NIR + n] = (float)v;
    }
}

// ---------------------------------------------------------------------------
// fp32 tiled GEMM 64x64x16 (MLP hidden layers + noise IR) — precision path.
// ---------------------------------------------------------------------------
__device__ inline float gelu_f(float x) {
    float x3 = x * x * x;
    float t = tanhf(0.7978845608028654f * (x + 0.044715f * x3));
    return 0.5f * x * (1.0f + t);
}

template<int MODE>
__global__ __launch_bounds__(256) void gemm_kernel(
    const float* __restrict__ A, const float* __restrict__ Bm,
    const float* __restrict__ bias, const float* __restrict__ resid,
    float* __restrict__ C, int M, int N, int K)
{
    __shared__ float As[16][68];
    __shared__ float Bs[16][68];
    const int tid = threadIdx.x;
    const int tx = tid & 15, ty = tid >> 4;
    const int m0 = blockIdx.x * 64;
    const int n0 = blockIdx.y * 64;
    const int ar  = tid >> 2;
    const int ac4 = (tid & 3) << 2;
    const int bk  = tid >> 4;
    const int bn4 = (tid & 15) << 2;
    float acc[4][4] = {};
    for (int k0 = 0; k0 < K; k0 += 16) {
        float4 av = *(const float4*)(A + (size_t)(m0 + ar) * K + k0 + ac4);
        As[ac4 + 0][ar] = av.x;
        As[ac4 + 1][ar] = av.y;
        As[ac4 + 2][ar] = av.z;
        As[ac4 + 3][ar] = av.w;
        const float* Bp = Bm + (size_t)(k0 + bk) * N + n0 + bn4;
        #pragma unroll
        for (int i = 0; i < 4; i++)
            Bs[bk][bn4 + i] = (n0 + bn4 + i < N) ? Bp[i] : 0.0f;
        __syncthreads();
        #pragma unroll
        for (int kk = 0; kk < 16; kk++) {
            float4 a4 = *(const float4*)&As[kk][ty << 2];
            float4 b4 = *(const float4*)&Bs[kk][tx << 2];
            float a[4] = {a4.x, a4.y, a4.z, a4.w};
            float b[4] = {b4.x, b4.y, b4.z, b4.w};
            #pragma unroll
            for (int i = 0; i < 4; i++)
                #pragma unroll
                for (int j = 0; j < 4; j++)
                    acc[i][j] = fmaf(a[i], b[j], acc[i][j]);
        }
        __syncthreads();
    }
    #pragma unroll
    for (int i = 0; i < 4; i++) {
        int m = m0 + (ty << 2) + i;
        #pragma unroll
        for (int j = 0; j < 4; j++) {
            int n = n0 + (tx << 2) + j;
            if (n < N) {
                float v = acc[i][j];
                if (bias) v += bias[n];
                if (MODE == 0) v = tanhf(v);
                else if (MODE == 1) v = resid[(size_t)m * N + n] + gelu_f(v);
                C[(size_t)m * N + n] = v;
            }
        }
    }
}

// ---------------------------------------------------------------------------
// bf16 MFMA GEMM: A [M][K] bf16, Bt [NPAD][K] bf16 (B transposed), C [M][NSTRIDE] fp32
// 128x128 tile, 4 waves (2x2), 64x64/wave, 16x16x32 MFMA.
// ---------------------------------------------------------------------------
template<int K, int NSTRIDE>
__global__ __launch_bounds__(256) void mfma_gemm(
    const unsigned short* __restrict__ A, const unsigned short* __restrict__ Bt,
    float* __restrict__ C, int M)
{
    __shared__ __align__(16) unsigned short As[128][72];
    __shared__ __align__(16) unsigned short Bs[128][72];
    const int tid = threadIdx.x;
    const int m0 = blockIdx.x * 128;
    const int n0 = blockIdx.y * 128;
    const int wid = tid >> 6;
    const int lane = tid & 63;
    const int wm = (wid >> 1) << 6;
    const int wn = (wid & 1) << 6;

    f32x4 acc[4][4];
    #pragma unroll
    for (int i = 0; i < 4; i++)
        #pragma unroll
        for (int j = 0; j < 4; j++)
            acc[i][j] = (f32x4){0.f, 0.f, 0.f, 0.f};

    for (int k0 = 0; k0 < K; k0 += 64) {
        #pragma unroll
        for (int s = 0; s < 4; s++) {
            int g = tid + (s << 8);
            int row = g >> 3;
            int kc = (g & 7) << 3;
            int ra = m0 + row; if (ra > M - 1) ra = M - 1;
            *(uint4*)&As[row][kc] = *(const uint4*)&A[(size_t)ra * K + k0 + kc];
            *(uint4*)&Bs[row][kc] = *(const uint4*)&Bt[(size_t)(n0 + row) * K + k0 + kc];
        }
        __syncthreads();
        #pragma unroll
        for (int kk = 0; kk < 64; kk += 32) {
            bf16x8 av[4], bv[4];
            const int koff = kk + ((lane >> 4) << 3);
            #pragma unroll
            for (int mt = 0; mt < 4; mt++)
                av[mt] = *(const bf16x8*)&As[wm + (mt << 4) + (lane & 15)][koff];
            #pragma unroll
            for (int nt = 0; nt < 4; nt++)
                bv[nt] = *(const bf16x8*)&Bs[wn + (nt << 4) + (lane & 15)][koff];
            #pragma unroll
            for (int mt = 0; mt < 4; mt++)
                #pragma unroll
                for (int nt = 0; nt < 4; nt++)
                    acc[mt][nt] = __builtin_amdgcn_mfma_f32_16x16x32_bf16(
                        av[mt], bv[nt], acc[mt][nt], 0, 0, 0);
        }
        __syncthreads();
    }
    const int cr0 = m0 + wm + ((lane >> 4) << 2);
    const int cc0 = n0 + wn + (lane & 15);
    #pragma unroll
    for (int mt = 0; mt < 4; mt++)
        #pragma unroll
        for (int nt = 0; nt < 4; nt++)
            #pragma unroll
            for (int j = 0; j < 4; j++) {
                int r = cr0 + (mt << 4) + j;
                if (r < M) C[(size_t)r * NSTRIDE + cc0 + (nt << 4)] = acc[mt][nt][j];
            }
}

// ---------------------------------------------------------------------------
// converts
// ---------------------------------------------------------------------------
__global__ __launch_bounds__(256) void convert_bf16(
    const float* __restrict__ X, __hip_bfloat16* __restrict__ Xb, int n)
{
    int i = blockIdx.x * 256 + threadIdx.x;
    if (i < n) Xb[i] = __float2bfloat16(X[i]);
}

__global__ __launch_bounds__(256) void convert_wout(
    const float* __restrict__ W, __hip_bfloat16* __restrict__ WTb)
{
    const int n = blockIdx.x;           // 0..639
    const int k = threadIdx.x;          // 0..255
    float v = (n < 593) ? W[(size_t)k * 593 + n] : 0.0f;
    WTb[(size_t)n * 256 + k] = __float2bfloat16(v);
}

// exact-fp32 f0 logit: f0logit[m] = sum_k h3[m][k]*W_out[k][0] + b_out[0]
__global__ __launch_bounds__(256) void f0_gemv(
    const float* __restrict__ h3, const float* __restrict__ Wout,
    const float* __restrict__ b_out, float* __restrict__ f0logit)
{
    const int row = blockIdx.x * 4 + (threadIdx.x >> 6);
    const int lane = threadIdx.x & 63;
    const float* a = h3 + (size_t)row * 256;
    float s = 0.0f;
    #pragma unroll
    for (int q = 0; q < 4; q++) {
        int k = lane + (q << 6);
        s = fmaf(a[k], Wout[(size_t)k * 593], s);
    }
    #pragma unroll
    for (int off = 32; off; off >>= 1) s += __shfl_down(s, off, 64);
    if (lane == 0) f0logit[row] = s + b_out[0];
}

// ---------------------------------------------------------------------------
// SP/NP from O[8000][640] cols 1..592 (+bias), fast-math exp_sigmoid
// ---------------------------------------------------------------------------
__global__ __launch_bounds__(256) void transform2_kernel(
    const float* __restrict__ O, const float* __restrict__ b_out,
    __hip_bfloat16* __restrict__ SPb, float* __restrict__ NP)
{
    int idx = blockIdx.x * 256 + threadIdx.x;
    if (idx >= 8000 * 592) return;
    int row = idx / 592;
    int c = idx - row * 592 + 1;
    float v = O[(size_t)row * 640 + c] + b_out[c];
    float s = 1.0f / (1.0f + __expf(-v));
    float p = 2.0f * __powf(s, 2.3025851f) + 1e-7f;
    if (c < 513) SPb[(size_t)row * 512 + (c - 1)] = __float2bfloat16(p);
    else         NP[(size_t)row * 80 + (c - 513)] = p;
}

// precise f0 (fp32 path preserved)
__global__ __launch_bounds__(256) void f0_kernel(
    const float* __restrict__ f0logit, float* __restrict__ f0w, float* __restrict__ f0out)
{
    int i = blockIdx.x * 256 + threadIdx.x;
    if (i >= 8000) return;
    float s = 1.0f / (1.0f + expf(-f0logit[i]));
    float f0 = 80.0f * powf(12.5f, s);
    if (f0 < 80.0f) f0 = 0.0f;
    f0w[i] = f0;
    f0out[i] = f0;
}

// ---------------------------------------------------------------------------
// fp64 frame-level pitch scan
// ---------------------------------------------------------------------------
__global__ void scan_kernel(const float* __restrict__ f0w, const float* __restrict__ iphase,
                            double* __restrict__ base, float* __restrict__ fph)
{
    int b = threadIdx.x;
    if (b >= 8) return;
    const float* f0 = f0w + b * 1000;
    double acc = 0.0;
    for (int f = 0; f < 1000; f++) {
        base[b * 1000 + f] = acc;
        double c  = (double)f0[f];
        double nx = (double)f0[(f < 999) ? (f + 1) : 999];
        acc += 120.5 * c + 119.5 * nx;
    }
    double u  = acc * (1.0 / 24000.0);
    double ph = TWO_PI_D * u + (double)iphase[b];
    fph[b] = (float)fmod(ph, TWO_PI_D);
}

// ---------------------------------------------------------------------------
// Sawtooth (fp64 phase) + threefry2x32 noise (bit-exact)
// ---------------------------------------------------------------------------
__device__ inline unsigned rotl32(unsigned x, int d) { return (x << d) | (x >> (32 - d)); }

__global__ __launch_bounds__(256) void saw_noise_kernel(
    const float* __restrict__ f0w, const double* __restrict__ base,
    const float* __restrict__ iphase, float* __restrict__ saw, float* __restrict__ nz)
{
    int idx = blockIdx.x * 256 + threadIdx.x;
    if (idx >= 8 * 240000) return;
    int b = idx / 240000;
    int t = idx - b * 240000;
    int f = t / 240;
    int r = t - f * 240;
    double c  = (double)f0w[b * 1000 + f];
    double nx = (double)f0w[b * 1000 + ((f < 999) ? (f + 1) : 999)];
    double rr = (double)r;
    double Bc = rr * (rr + 1.0) * (1.0 / 480.0);
    double Ac = (rr + 1.0) - Bc;
    double cum = base[b * 1000 + f] + Ac * c + Bc * nx;
    double u  = cum * (1.0 / 24000.0) + (double)iphase[b] * (1.0 / TWO_PI_D);
    double fr = u - floor(u);
    saw[idx] = (float)(2.0 * fr - 1.0);

    const unsigned n2 = 960000u;
    unsigned mi = (unsigned)idx;
    unsigned i0 = (mi < n2) ? mi : (mi - n2);
    unsigned x0 = i0, x1 = i0 + n2;
    const unsigned ks0 = 0u, ks1 = 123u, ks2 = 0x1BD11BDAu ^ 0u ^ 123u;
    x0 += ks0; x1 += ks1;
#define TF_R(rot) { x0 += x1; x1 = rotl32(x1, rot); x1 ^= x0; }
    TF_R(13) TF_R(15) TF_R(26) TF_R(6)
    x0 += ks1; x1 += ks2 + 1u;
    TF_R(17) TF_R(29) TF_R(16) TF_R(24)
    x0 += ks2; x1 += ks0 + 2u;
    TF_R(13) TF_R(15) TF_R(26) TF_R(6)
    x0 += ks0; x1 += ks1 + 3u;
    TF_R(17) TF_R(29) TF_R(16) TF_R(24)
    x0 += ks1; x1 += ks2 + 4u;
    TF_R(13) TF_R(15) TF_R(26) TF_R(6)
    x0 += ks2; x1 += ks0 + 5u;
#undef TF_R
    unsigned bits = (mi < n2) ? x0 : x1;
    float uf = __uint_as_float((bits >> 9) | 0x3f800000u) - 1.0f;
    nz[idx] = uf * 2.0f - 1.0f;
}

// ---------------------------------------------------------------------------
// Per-frame conv, harmonic. 4 frames/block, 80 thr/frame (fr = tid&3, bank-
// spread), 16 outputs/thread, 20-reg rolling IR window. IR stride 1024.
// ---------------------------------------------------------------------------
__global__ __launch_bounds__(320) void frameconv_h(
    const float* __restrict__ audio, const float* __restrict__ IR,
    float* __restrict__ Y, int fstart, int nfc)
{
    // per-frame w stride 1572 floats: 1572 % 32 == 4 -> frames land on
    // different bank quads; raw[8+x] = wf[x], data wf[240..1262)
    __shared__ __align__(16) float u_s[4][240];
    __shared__ __align__(16) float w_raw[4][1572];
    const int fl0 = blockIdx.x * 4;
    const int b = blockIdx.y;
    const int tid = threadIdx.x;
    const int nfr = min(4, nfc - fl0);

    for (int i = tid; i < nfr * 522; i += 320) {
        int fr = i / 522, r = i - fr * 522;
        w_raw[fr][r < 248 ? r : (r - 248 + 1270)] = 0.0f;
    }
    for (int i = tid; i < nfr * 1022; i += 320) {
        int fr = i / 1022, d = i - fr * 1022;
        w_raw[fr][248 + d] = IR[((size_t)b * 1000 + fstart + fl0 + fr) * 1024 + d];
    }
    for (int i = tid; i < nfr * 240; i += 320) {
        int fr = i / 240, r = i - fr * 240;
        u_s[fr][r] = audio[(size_t)b * 240000 + (size_t)(fstart + fl0 + fr) * 240 + r];
    }
    __syncthreads();

    const int fr = tid & 3;
    const int j0 = (tid >> 2) << 4;      // 0..1264
    if (fr < nfr) {
        const float* uf = u_s[fr];
        const float* wf = &w_raw[fr][8];
        float acc[16];
        #pragma unroll
        for (int q = 0; q < 16; q++) acc[q] = 0.0f;
        int base = 240 + j0;
        float wv[20];
        #pragma unroll
        for (int cc = 0; cc < 5; cc++) {
            float4 t4 = *(const float4*)&wf[base - 4 + 4 * cc];
            wv[4*cc+0] = t4.x; wv[4*cc+1] = t4.y; wv[4*cc+2] = t4.z; wv[4*cc+3] = t4.w;
        }
        #pragma unroll 5
        for (int i = 0; i < 240; i += 4) {
            float4 u4 = *(const float4*)&uf[i];
            float uu[4] = {u4.x, u4.y, u4.z, u4.w};
            #pragma unroll
            for (int q = 0; q < 16; q++)
                #pragma unroll
                for (int k = 0; k < 4; k++)
                    acc[q] = fmaf(uu[k], wv[q - k + 4], acc[q]);
            #pragma unroll
            for (int d = 19; d >= 4; d--) wv[d] = wv[d - 4];
            float4 nw = *(const float4*)&wf[base - 8];
            wv[0] = nw.x; wv[1] = nw.y; wv[2] = nw.z; wv[3] = nw.w;
            base -= 4;
        }
        float* yp = &Y[((size_t)b * nfc + fl0 + fr) * 1280 + j0];
        #pragma unroll
        for (int cc = 0; cc < 4; cc++) {
            float4 r4 = {acc[4*cc], acc[4*cc+1], acc[4*cc+2], acc[4*cc+3]};
            *(float4*)&yp[4*cc] = r4;
        }
    }
}

// ---------------------------------------------------------------------------
// Per-frame conv, noise (unchanged from r2): iterate IR, window over audio.
// ---------------------------------------------------------------------------
#define CONV_GROUP(u4) \
    a0 = fmaf(u4.x, Whi.x, a0); a1 = fmaf(u4.x, Whi.y, a1); a2 = fmaf(u4.x, Whi.z, a2); a3 = fmaf(u4.x, Whi.w, a3); \
    a0 = fmaf(u4.y, Wlo.w, a0); a1 = fmaf(u4.y, Whi.x, a1); a2 = fmaf(u4.y, Whi.y, a2); a3 = fmaf(u4.y, Whi.z, a3); \
    a0 = fmaf(u4.z, Wlo.z, a0); a1 = fmaf(u4.z, Wlo.w, a1); a2 = fmaf(u4.z, Whi.x, a2); a3 = fmaf(u4.z, Whi.y, a3); \
    a0 = fmaf(u4.w, Wlo.y, a0); a1 = fmaf(u4.w, Wlo.z, a1); a2 = fmaf(u4.w, Wlo.w, a2); a3 = fmaf(u4.w, Whi.x, a3);

__global__ __launch_bounds__(128) void frameconv_n(
    const float* __restrict__ audio, const float* __restrict__ IR,
    float* __restrict__ Y, int fstart, int nfc)
{
    __shared__ __align__(16) float u_s[160];
    __shared__ __align__(16) float w_s[560];
    const int fl = blockIdx.x;
    const int b  = blockIdx.y;
    const int f  = fstart + fl;
    const int tid = threadIdx.x;
    const float* irow = IR + ((size_t)b * 1000 + f) * 158;
    for (int i = tid; i < 160; i += 128) {
        u_s[i] = (i < 158) ? irow[i] : 0.0f;
        w_s[i] = 0.0f;
        w_s[400 + i] = 0.0f;
    }
    for (int i = tid; i < 240; i += 128)
        w_s[160 + i] = audio[(size_t)b * 240000 + (size_t)f * 240 + i];
    __syncthreads();

    const int j0 = tid << 2;
    if (j0 >= 400) return;
    int base = 160 + j0 - 4;
    float4 Wlo = *(const float4*)&w_s[base];
    float4 Whi = *(const float4*)&w_s[base + 4];
    float a0 = 0.f, a1 = 0.f, a2 = 0.f, a3 = 0.f;
    #pragma unroll 4
    for (int t = 0; t < 156; t += 4) {
        float4 u4 = *(const float4*)&u_s[t];
        CONV_GROUP(u4)
        Whi = Wlo;
        base -= 4;
        Wlo = *(const float4*)&w_s[base];
    }
    {
        float4 u4 = *(const float4*)&u_s[156];
        CONV_GROUP(u4)
    }
    float4 r; r.x = a0; r.y = a1; r.z = a2; r.w = a3;
    *(float4*)&Y[((size_t)b * nfc + fl) * 400 + j0] = r;
}

// ---------------------------------------------------------------------------
// Overlap-add + 'same' slice + outputs
// ---------------------------------------------------------------------------
__global__ __launch_bounds__(256) void combine_kernel(
    const float* __restrict__ Yh, const float* __restrict__ Yn,
    int fstart, int nfc, int t0c, int tcnt,
    float* __restrict__ sig, float* __restrict__ harm, float* __restrict__ noise)
{
    int idx = blockIdx.x * 256 + threadIdx.x;
    if (idx >= tcnt) return;
    const int b = blockIdx.y;
    const int t = t0c + idx;
    float hsum = 0.0f;
    const int fhi = (t + 509) / 240;
    #pragma unroll
    for (int q = 0; q < 6; q++) {
        int f = fhi - q;
        int j = t + 509 - 240 * f;
        if (f >= 0 && f < 1000 && j < 1261)
            hsum += Yh[((size_t)b * nfc + (f - fstart)) * 1280 + j];
    }
    float nsum = 0.0f;
    const int ghi = (t + 77) / 240;
    #pragma unroll
    for (int q = 0; q < 2; q++) {
        int f = ghi - q;
        int j = t + 77 - 240 * f;
        if (f >= 0 && f < 1000 && j < 397)
            nsum += Yn[((size_t)b * nfc + (f - fstart)) * 400 + j];
    }
    size_t o = (size_t)b * 240000 + t;
    harm[o]  = hsum;
    noise[o] = nsum;
    sig[o]   = hsum + nsum;
}

// ---------------------------------------------------------------------------
extern "C" void kernel_launch(void* const* d_in, const int* in_sizes, int n_in,
                              void* d_out, int out_size, void* d_ws, size_t ws_size,
                              hipStream_t stream)
{
    (void)in_sizes; (void)n_in; (void)out_size; (void)ws_size;
    const float* mel    = (const float*)d_in[0];
    const float* iphase = (const float*)d_in[1];
    const float* W_in   = (const float*)d_in[2];
    const float* b_in   = (const float*)d_in[3];
    const float* W1     = (const float*)d_in[4];
    const float* b1     = (const float*)d_in[5];
    const float* W2     = (const float*)d_in[6];
    const float* b2     = (const float*)d_in[7];
    const float* W_out  = (const float*)d_in[8];
    const float* b_out  = (const float*)d_in[9];
    float* ws = (float*)d_ws;

    // workspace layout (float offsets), peak 18,898,560 floats
    __hip_bfloat16* Chb = (__hip_bfloat16*)(ws + 0);        // [1024][512] bf16
    float*  Cn      = ws + 262144;                          // 12,640
    __hip_bfloat16* SPb = (__hip_bfloat16*)(ws + 274784);   // [8000][512] bf16
    float*  NP      = ws + 2322784;                         // 640,000
    // [0, 3,440,640) is reused for YhC/YnC during convs (all above dead then)
    float*  YhC     = ws + 0;                               // 2,621,440
    float*  YnC     = ws + 2621440;                         // 819,200
    float*  f0w     = ws + 3440640;                         // 8,000
    double* base    = (double*)(ws + 3448640);              // 8,000 dbl
    float*  f0logit = ws + 3464640;                         // 8,000
    float*  saw     = ws + 3472640;                         // 1,920,000
    float*  nz      = ws + 5392640;                         // 1,920,000
    float*  BA      = ws + 7312640;                         // 2,048,000 (h1,h3)
    float*  BB      = ws + 9360640;                         // 2,048,000 (h2)
    __hip_bfloat16* BAb = (__hip_bfloat16*)(ws + 11408640); // [8000][256] bf16
    __hip_bfloat16* WTb = (__hip_bfloat16*)(ws + 12432640); // [640][256] bf16
    float*  O       = ws + 12514560;                        // [8000][640] = 5,120,000
    float*  IRh     = ws + 7312640;                         // [8000][1024] (aliases BA..O, dead)
    float*  IRn     = ws + 17634560;                        // 1,264,000

    float* out       = (float*)d_out;
    float* sig_out   = out;
    float* f0_out    = out + 1920000;
    float* fph_out   = out + 1928000;
    float* harm_out  = out + 1928008;
    float* noise_out = out + 3848008;

    basis_h_bf16_t<<<1024, 256, 0, stream>>>(Chb);
    basis_kernel<80, 158><<<80, 256, 0, stream>>>(Cn);

    // MLP hidden layers in fp32 (f0-precision path)
    gemm_kernel<0><<<dim3(125, 4), 256, 0, stream>>>(mel, W_in, b_in, nullptr, BA, 8000, 256, 80);
    gemm_kernel<1><<<dim3(125, 4), 256, 0, stream>>>(BA,  W1,   b1,   BA,      BB, 8000, 256, 256);
    gemm_kernel<1><<<dim3(125, 4), 256, 0, stream>>>(BB,  W2,   b2,   BB,      BA, 8000, 256, 256);

    // W_out: bf16 MFMA for SP/NP columns + exact fp32 GEMV for f0 column
    convert_bf16<<<(2048000 + 255) / 256, 256, 0, stream>>>(BA, BAb, 2048000);
    convert_wout<<<640, 256, 0, stream>>>(W_out, WTb);
    mfma_gemm<256, 640><<<dim3(63, 5), 256, 0, stream>>>(
        (const unsigned short*)BAb, (const unsigned short*)WTb, O, 8000);
    f0_gemv<<<2000, 256, 0, stream>>>(BA, W_out, b_out, f0logit);

    transform2_kernel<<<(8000 * 592 + 255) / 256, 256, 0, stream>>>(O, b_out, SPb, NP);
    f0_kernel<<<(8000 + 255) / 256, 256, 0, stream>>>(f0logit, f0w, f0_out);
    scan_kernel<<<1, 64, 0, stream>>>(f0w, iphase, base, fph_out);
    saw_noise_kernel<<<(1920000 + 255) / 256, 256, 0, stream>>>(f0w, base, iphase, saw, nz);

    // IR_h = SPb @ Chb^T  (bf16 MFMA, fp32 out, stride 1024)
    mfma_gemm<512, 1024><<<dim3(63, 8), 256, 0, stream>>>(
        (const unsigned short*)SPb, (const unsigned short*)Chb, IRh, 8000);
    // IR_n fp32
    gemm_kernel<2><<<dim3(125, 3), 256, 0, stream>>>(NP, Cn, nullptr, nullptr, IRn, 8000, 158, 80);

    // chunked per-frame conv + overlap-add
    for (int c = 0; c < 4; c++) {
        int fs   = (c == 0) ? 0 : (250 * c - 3);
        int fe   = (c == 3) ? 1000 : (250 * (c + 1) + 3);
        int nfc  = fe - fs;                          // 253,256,256,253
        int t0c  = 250 * 240 * c;
        int tcnt = 60000;
        frameconv_h<<<dim3((nfc + 3) / 4, 8), 320, 0, stream>>>(saw, IRh, YhC, fs, nfc);
        frameconv_n<<<dim3(nfc, 8), 128, 0, stream>>>(nz, IRn, YnC, fs, nfc);
        combine_kernel<<<dim3((tcnt + 255) / 256, 8), 256, 0, stream>>>(
            YhC, YnC, fs, nfc, t0c, tcnt, sig_out, harm_out, noise_out);
    }
}

// Round 4
// 350.800 us; speedup vs baseline: 2.6463x; 1.1544x over previous
//
#include <hip/hip_runtime.h>
#include <hip/hip_bf16.h>
#include <math.h>

#define TWO_PI_D 6.283185307179586476925286766559
#define TWO_PI_F 6.28318530718f

typedef short bf16x8 __attribute__((ext_vector_type(8)));
typedef float f32x4 __attribute__((ext_vector_type(4)));

// ---------------------------------------------------------------------------
// Harmonic basis, bf16, TRANSPOSED + padded: Ct[n][k], n<1024 (1022 valid), k<512
// ---------------------------------------------------------------------------
__global__ __launch_bounds__(256) void basis_h_bf16_t(__hip_bfloat16* __restrict__ Ct)
{
    const int n = blockIdx.x;            // 0..1023
    for (int k = threadIdx.x; k < 512; k += 256) {
        float v = 0.0f;
        if (n < 1022) {
            float hann = 0.5f * (1.0f - cosf(TWO_PI_F * (float)n / 1022.0f));
            float w = hann * (1.0f / 1022.0f);
            if (k == 0) v = w;
            else if (k == 511) v = (n & 1) ? w : -w;
            else {
                int m = (k * n) % 1022;
                float c = cosf(TWO_PI_F * (float)m / 1022.0f);
                v = 2.0f * w * ((k & 1) ? -c : c);
            }
        }
        Ct[(size_t)n * 512 + k] = __float2bfloat16(v);
    }
}

// noise basis, fp32: C[k][n], k<80, n<158
template<int NMAG, int NIR>
__global__ __launch_bounds__(256) void basis_kernel(float* __restrict__ C)
{
    const int k = blockIdx.x;
    for (int n = threadIdx.x; n < NIR; n += blockDim.x) {
        double hann = 0.5 * (1.0 - cos(TWO_PI_D * (double)n / (double)NIR));
        double w = hann / (double)NIR;
        double v;
        if (k == 0) v = w;
        else if (k == NMAG - 1) v = (n & 1) ? w : -w;
        else {
            long m = ((long)k * (long)n) % NIR;
            double c = cos(TWO_PI_D * (double)m / (double)NIR);
            v = 2.0 * w * ((k & 1) ? -c : c);
        }
        C[(size_t)k * NIR + n] = (float)v;
    }
}

// ---------------------------------------------------------------------------
// fp32 tiled GEMM 64x64x16 (MLP hidden layers + noise IR) — precision path.
// MODE 1 optionally mirrors output to bf16 (Cb).
// ---------------------------------------------------------------------------
__device__ inline float gelu_f(float x) {
    float x3 = x * x * x;
    float t = tanhf(0.7978845608028654f * (x + 0.044715f * x3));
    return 0.5f * x * (1.0f + t);
}

template<int MODE>
__global__ __launch_bounds__(256) void gemm_kernel(
    const float* __restrict__ A, const float* __restrict__ Bm,
    const float* __restrict__ bias, const float* __restrict__ resid,
    float* __restrict__ C, __hip_bfloat16* __restrict__ Cb, int M, int N, int K)
{
    __shared__ float As[16][68];
    __shared__ float Bs[16][68];
    const int tid = threadIdx.x;
    const int tx = tid & 15, ty = tid >> 4;
    const int m0 = blockIdx.x * 64;
    const int n0 = blockIdx.y * 64;
    const int ar  = tid >> 2;
    const int ac4 = (tid & 3) << 2;
    const int bk  = tid >> 4;
    const int bn4 = (tid & 15) << 2;
    float acc[4][4] = {};
    for (int k0 = 0; k0 < K; k0 += 16) {
        float4 av = *(const float4*)(A + (size_t)(m0 + ar) * K + k0 + ac4);
        As[ac4 + 0][ar] = av.x;
        As[ac4 + 1][ar] = av.y;
        As[ac4 + 2][ar] = av.z;
        As[ac4 + 3][ar] = av.w;
        const float* Bp = Bm + (size_t)(k0 + bk) * N + n0 + bn4;
        #pragma unroll
        for (int i = 0; i < 4; i++)
            Bs[bk][bn4 + i] = (n0 + bn4 + i < N) ? Bp[i] : 0.0f;
        __syncthreads();
        #pragma unroll
        for (int kk = 0; kk < 16; kk++) {
            float4 a4 = *(const float4*)&As[kk][ty << 2];
            float4 b4 = *(const float4*)&Bs[kk][tx << 2];
            float a[4] = {a4.x, a4.y, a4.z, a4.w};
            float b[4] = {b4.x, b4.y, b4.z, b4.w};
            #pragma unroll
            for (int i = 0; i < 4; i++)
                #pragma unroll
                for (int j = 0; j < 4; j++)
                    acc[i][j] = fmaf(a[i], b[j], acc[i][j]);
        }
        __syncthreads();
    }
    #pragma unroll
    for (int i = 0; i < 4; i++) {
        int m = m0 + (ty << 2) + i;
        #pragma unroll
        for (int j = 0; j < 4; j++) {
            int n = n0 + (tx << 2) + j;
            if (n < N) {
                float v = acc[i][j];
                if (bias) v += bias[n];
                if (MODE == 0) v = tanhf(v);
                else if (MODE == 1) v = resid[(size_t)m * N + n] + gelu_f(v);
                C[(size_t)m * N + n] = v;
                if (MODE == 1 && Cb) Cb[(size_t)m * N + n] = __float2bfloat16(v);
            }
        }
    }
}

// ---------------------------------------------------------------------------
// bf16 MFMA GEMM: A [M][K] bf16, Bt [NPAD][K] bf16, C [M][NSTRIDE] fp32
// ---------------------------------------------------------------------------
template<int K, int NSTRIDE>
__global__ __launch_bounds__(256) void mfma_gemm(
    const unsigned short* __restrict__ A, const unsigned short* __restrict__ Bt,
    float* __restrict__ C, int M)
{
    __shared__ __align__(16) unsigned short As[128][72];
    __shared__ __align__(16) unsigned short Bs[128][72];
    const int tid = threadIdx.x;
    const int m0 = blockIdx.x * 128;
    const int n0 = blockIdx.y * 128;
    const int wid = tid >> 6;
    const int lane = tid & 63;
    const int wm = (wid >> 1) << 6;
    const int wn = (wid & 1) << 6;

    f32x4 acc[4][4];
    #pragma unroll
    for (int i = 0; i < 4; i++)
        #pragma unroll
        for (int j = 0; j < 4; j++)
            acc[i][j] = (f32x4){0.f, 0.f, 0.f, 0.f};

    for (int k0 = 0; k0 < K; k0 += 64) {
        #pragma unroll
        for (int s = 0; s < 4; s++) {
            int g = tid + (s << 8);
            int row = g >> 3;
            int kc = (g & 7) << 3;
            int ra = m0 + row; if (ra > M - 1) ra = M - 1;
            *(uint4*)&As[row][kc] = *(const uint4*)&A[(size_t)ra * K + k0 + kc];
            *(uint4*)&Bs[row][kc] = *(const uint4*)&Bt[(size_t)(n0 + row) * K + k0 + kc];
        }
        __syncthreads();
        #pragma unroll
        for (int kk = 0; kk < 64; kk += 32) {
            bf16x8 av[4], bv[4];
            const int koff = kk + ((lane >> 4) << 3);
            #pragma unroll
            for (int mt = 0; mt < 4; mt++)
                av[mt] = *(const bf16x8*)&As[wm + (mt << 4) + (lane & 15)][koff];
            #pragma unroll
            for (int nt = 0; nt < 4; nt++)
                bv[nt] = *(const bf16x8*)&Bs[wn + (nt << 4) + (lane & 15)][koff];
            #pragma unroll
            for (int mt = 0; mt < 4; mt++)
                #pragma unroll
                for (int nt = 0; nt < 4; nt++)
                    acc[mt][nt] = __builtin_amdgcn_mfma_f32_16x16x32_bf16(
                        av[mt], bv[nt], acc[mt][nt], 0, 0, 0);
        }
        __syncthreads();
    }
    const int cr0 = m0 + wm + ((lane >> 4) << 2);
    const int cc0 = n0 + wn + (lane & 15);
    #pragma unroll
    for (int mt = 0; mt < 4; mt++)
        #pragma unroll
        for (int nt = 0; nt < 4; nt++)
            #pragma unroll
            for (int j = 0; j < 4; j++) {
                int r = cr0 + (mt << 4) + j;
                if (r < M) C[(size_t)r * NSTRIDE + cc0 + (nt << 4)] = acc[mt][nt][j];
            }
}

// ---------------------------------------------------------------------------
__global__ __launch_bounds__(256) void convert_wout(
    const float* __restrict__ W, __hip_bfloat16* __restrict__ WTb)
{
    const int n = blockIdx.x;           // 0..639
    const int k = threadIdx.x;          // 0..255
    float v = (n < 593) ? W[(size_t)k * 593 + n] : 0.0f;
    WTb[(size_t)n * 256 + k] = __float2bfloat16(v);
}

// exact-fp32 f0 logit + fused precise f0 transform
__global__ __launch_bounds__(256) void f0_gemv(
    const float* __restrict__ h3, const float* __restrict__ Wout,
    const float* __restrict__ b_out, float* __restrict__ f0w, float* __restrict__ f0out)
{
    const int row = blockIdx.x * 4 + (threadIdx.x >> 6);
    const int lane = threadIdx.x & 63;
    const float* a = h3 + (size_t)row * 256;
    float s = 0.0f;
    #pragma unroll
    for (int q = 0; q < 4; q++) {
        int k = lane + (q << 6);
        s = fmaf(a[k], Wout[(size_t)k * 593], s);
    }
    #pragma unroll
    for (int off = 32; off; off >>= 1) s += __shfl_down(s, off, 64);
    if (lane == 0) {
        float lg = s + b_out[0];
        float sg = 1.0f / (1.0f + expf(-lg));
        float f0 = 80.0f * powf(12.5f, sg);
        if (f0 < 80.0f) f0 = 0.0f;
        f0w[row] = f0;
        f0out[row] = f0;
    }
}

// ---------------------------------------------------------------------------
// SP/NP from O[8000][640] cols 1..592 (+bias), fast-math exp_sigmoid
// ---------------------------------------------------------------------------
__global__ __launch_bounds__(256) void transform2_kernel(
    const float* __restrict__ O, const float* __restrict__ b_out,
    __hip_bfloat16* __restrict__ SPb, float* __restrict__ NP)
{
    int idx = blockIdx.x * 256 + threadIdx.x;
    if (idx >= 8000 * 592) return;
    int row = idx / 592;
    int c = idx - row * 592 + 1;
    float v = O[(size_t)row * 640 + c] + b_out[c];
    float s = 1.0f / (1.0f + __expf(-v));
    float p = 2.0f * __powf(s, 2.3025851f) + 1e-7f;
    if (c < 513) SPb[(size_t)row * 512 + (c - 1)] = __float2bfloat16(p);
    else         NP[(size_t)row * 80 + (c - 513)] = p;
}

// ---------------------------------------------------------------------------
// Parallel fp64 frame-level pitch scan: 8 blocks x 256 threads, 4 frames/thread.
// ---------------------------------------------------------------------------
__device__ inline double shfl_up_d(double x, int off) {
    long long l = __double_as_longlong(x);
    int lo = (int)(l & 0xffffffffLL);
    int hi = (int)(l >> 32);
    lo = __shfl_up(lo, off, 64);
    hi = __shfl_up(hi, off, 64);
    return __longlong_as_double(((long long)hi << 32) | (unsigned int)lo);
}

__global__ __launch_bounds__(256) void scan_par_kernel(
    const float* __restrict__ f0w, const float* __restrict__ iphase,
    double* __restrict__ base, float* __restrict__ fph)
{
    __shared__ double wsum[4];
    const int b = blockIdx.x;
    const int tid = threadIdx.x;
    const int lane = tid & 63;
    const float* f0 = f0w + b * 1000;
    double s[4];
    double loc = 0.0;
    #pragma unroll
    for (int q = 0; q < 4; q++) {
        int f = tid * 4 + q;
        s[q] = loc;
        if (f < 1000) {
            double c  = (double)f0[f];
            double nx = (double)f0[(f < 999) ? (f + 1) : 999];
            loc += 120.5 * c + 119.5 * nx;
        }
    }
    // inclusive wave scan of loc
    double v = loc;
    #pragma unroll
    for (int off = 1; off < 64; off <<= 1) {
        double o = shfl_up_d(v, off);
        if (lane >= off) v += o;
    }
    if (lane == 63) wsum[tid >> 6] = v;
    __syncthreads();
    double wpre = 0.0;
    const int w = tid >> 6;
    for (int i = 0; i < w; i++) wpre += wsum[i];
    const double excl = wpre + v - loc;
    #pragma unroll
    for (int q = 0; q < 4; q++) {
        int f = tid * 4 + q;
        if (f < 1000) base[b * 1000 + f] = excl + s[q];
    }
    if (tid == 255) {
        double total = excl + loc;
        double u  = total * (1.0 / 24000.0);
        double ph = TWO_PI_D * u + (double)iphase[b];
        fph[b] = (float)fmod(ph, TWO_PI_D);
    }
}

// ---------------------------------------------------------------------------
// Sawtooth (fp64 phase) + threefry2x32 noise (bit-exact)
// ---------------------------------------------------------------------------
__device__ inline unsigned rotl32(unsigned x, int d) { return (x << d) | (x >> (32 - d)); }

__global__ __launch_bounds__(256) void saw_noise_kernel(
    const float* __restrict__ f0w, const double* __restrict__ base,
    const float* __restrict__ iphase, float* __restrict__ saw, float* __restrict__ nz)
{
    int idx = blockIdx.x * 256 + threadIdx.x;
    if (idx >= 8 * 240000) return;
    int b = idx / 240000;
    int t = idx - b * 240000;
    int f = t / 240;
    int r = t - f * 240;
    double c  = (double)f0w[b * 1000 + f];
    double nx = (double)f0w[b * 1000 + ((f < 999) ? (f + 1) : 999)];
    double rr = (double)r;
    double Bc = rr * (rr + 1.0) * (1.0 / 480.0);
    double Ac = (rr + 1.0) - Bc;
    double cum = base[b * 1000 + f] + Ac * c + Bc * nx;
    double u  = cum * (1.0 / 24000.0) + (double)iphase[b] * (1.0 / TWO_PI_D);
    double fr = u - floor(u);
    saw[idx] = (float)(2.0 * fr - 1.0);

    const unsigned n2 = 960000u;
    unsigned mi = (unsigned)idx;
    unsigned i0 = (mi < n2) ? mi : (mi - n2);
    unsigned x0 = i0, x1 = i0 + n2;
    const unsigned ks0 = 0u, ks1 = 123u, ks2 = 0x1BD11BDAu ^ 0u ^ 123u;
    x0 += ks0; x1 += ks1;
#define TF_R(rot) { x0 += x1; x1 = rotl32(x1, rot); x1 ^= x0; }
    TF_R(13) TF_R(15) TF_R(26) TF_R(6)
    x0 += ks1; x1 += ks2 + 1u;
    TF_R(17) TF_R(29) TF_R(16) TF_R(24)
    x0 += ks2; x1 += ks0 + 2u;
    TF_R(13) TF_R(15) TF_R(26) TF_R(6)
    x0 += ks0; x1 += ks1 + 3u;
    TF_R(17) TF_R(29) TF_R(16) TF_R(24)
    x0 += ks1; x1 += ks2 + 4u;
    TF_R(13) TF_R(15) TF_R(26) TF_R(6)
    x0 += ks2; x1 += ks0 + 5u;
#undef TF_R
    unsigned bits = (mi < n2) ? x0 : x1;
    float uf = __uint_as_float((bits >> 9) | 0x3f800000u) - 1.0f;
    nz[idx] = uf * 2.0f - 1.0f;
}

// ---------------------------------------------------------------------------
// Per-frame conv, harmonic. 4 frames/block, 80 thr/frame, 16 outputs/thread.
// ---------------------------------------------------------------------------
__global__ __launch_bounds__(320) void frameconv_h(
    const float* __restrict__ audio, const float* __restrict__ IR,
    float* __restrict__ Y, int fstart, int nfc)
{
    __shared__ __align__(16) float u_s[4][240];
    __shared__ __align__(16) float w_raw[4][1572];
    const int fl0 = blockIdx.x * 4;
    const int b = blockIdx.y;
    const int tid = threadIdx.x;
    const int nfr = min(4, nfc - fl0);

    for (int i = tid; i < nfr * 522; i += 320) {
        int fr = i / 522, r = i - fr * 522;
        w_raw[fr][r < 248 ? r : (r - 248 + 1270)] = 0.0f;
    }
    for (int i = tid; i < nfr * 1022; i += 320) {
        int fr = i / 1022, d = i - fr * 1022;
        w_raw[fr][248 + d] = IR[((size_t)b * 1000 + fstart + fl0 + fr) * 1024 + d];
    }
    for (int i = tid; i < nfr * 240; i += 320) {
        int fr = i / 240, r = i - fr * 240;
        u_s[fr][r] = audio[(size_t)b * 240000 + (size_t)(fstart + fl0 + fr) * 240 + r];
    }
    __syncthreads();

    const int fr = tid & 3;
    const int j0 = (tid >> 2) << 4;
    if (fr < nfr) {
        const float* uf = u_s[fr];
        const float* wf = &w_raw[fr][8];
        float acc[16];
        #pragma unroll
        for (int q = 0; q < 16; q++) acc[q] = 0.0f;
        int base = 240 + j0;
        float wv[20];
        #pragma unroll
        for (int cc = 0; cc < 5; cc++) {
            float4 t4 = *(const float4*)&wf[base - 4 + 4 * cc];
            wv[4*cc+0] = t4.x; wv[4*cc+1] = t4.y; wv[4*cc+2] = t4.z; wv[4*cc+3] = t4.w;
        }
        #pragma unroll 5
        for (int i = 0; i < 240; i += 4) {
            float4 u4 = *(const float4*)&uf[i];
            float uu[4] = {u4.x, u4.y, u4.z, u4.w};
            #pragma unroll
            for (int q = 0; q < 16; q++)
                #pragma unroll
                for (int k = 0; k < 4; k++)
                    acc[q] = fmaf(uu[k], wv[q - k + 4], acc[q]);
            #pragma unroll
            for (int d = 19; d >= 4; d--) wv[d] = wv[d - 4];
            float4 nw = *(const float4*)&wf[base - 8];
            wv[0] = nw.x; wv[1] = nw.y; wv[2] = nw.z; wv[3] = nw.w;
            base -= 4;
        }
        float* yp = &Y[((size_t)b * nfc + fl0 + fr) * 1280 + j0];
        #pragma unroll
        for (int cc = 0; cc < 4; cc++) {
            float4 r4 = {acc[4*cc], acc[4*cc+1], acc[4*cc+2], acc[4*cc+3]};
            *(float4*)&yp[4*cc] = r4;
        }
    }
}

// ---------------------------------------------------------------------------
// Per-frame conv, noise: iterate IR, window over audio.
// ---------------------------------------------------------------------------
#define CONV_GROUP(u4) \
    a0 = fmaf(u4.x, Whi.x, a0); a1 = fmaf(u4.x, Whi.y, a1); a2 = fmaf(u4.x, Whi.z, a2); a3 = fmaf(u4.x, Whi.w, a3); \
    a0 = fmaf(u4.y, Wlo.w, a0); a1 = fmaf(u4.y, Whi.x, a1); a2 = fmaf(u4.y, Whi.y, a2); a3 = fmaf(u4.y, Whi.z, a3); \
    a0 = fmaf(u4.z, Wlo.z, a0); a1 = fmaf(u4.z, Wlo.w, a1); a2 = fmaf(u4.z, Whi.x, a2); a3 = fmaf(u4.z, Whi.y, a3); \
    a0 = fmaf(u4.w, Wlo.y, a0); a1 = fmaf(u4.w, Wlo.z, a1); a2 = fmaf(u4.w, Wlo.w, a2); a3 = fmaf(u4.w, Whi.x, a3);

__global__ __launch_bounds__(128) void frameconv_n(
    const float* __restrict__ audio, const float* __restrict__ IR,
    float* __restrict__ Y, int fstart, int nfc)
{
    __shared__ __align__(16) float u_s[160];
    __shared__ __align__(16) float w_s[560];
    const int fl = blockIdx.x;
    const int b  = blockIdx.y;
    const int f  = fstart + fl;
    const int tid = threadIdx.x;
    const float* irow = IR + ((size_t)b * 1000 + f) * 158;
    for (int i = tid; i < 160; i += 128) {
        u_s[i] = (i < 158) ? irow[i] : 0.0f;
        w_s[i] = 0.0f;
        w_s[400 + i] = 0.0f;
    }
    for (int i = tid; i < 240; i += 128)
        w_s[160 + i] = audio[(size_t)b * 240000 + (size_t)f * 240 + i];
    __syncthreads();

    const int j0 = tid << 2;
    if (j0 >= 400) return;
    int base = 160 + j0 - 4;
    float4 Wlo = *(const float4*)&w_s[base];
    float4 Whi = *(const float4*)&w_s[base + 4];
    float a0 = 0.f, a1 = 0.f, a2 = 0.f, a3 = 0.f;
    #pragma unroll 4
    for (int t = 0; t < 156; t += 4) {
        float4 u4 = *(const float4*)&u_s[t];
        CONV_GROUP(u4)
        Whi = Wlo;
        base -= 4;
        Wlo = *(const float4*)&w_s[base];
    }
    {
        float4 u4 = *(const float4*)&u_s[156];
        CONV_GROUP(u4)
    }
    float4 r; r.x = a0; r.y = a1; r.z = a2; r.w = a3;
    *(float4*)&Y[((size_t)b * nfc + fl) * 400 + j0] = r;
}

// ---------------------------------------------------------------------------
// Overlap-add + 'same' slice + outputs
// ---------------------------------------------------------------------------
__global__ __launch_bounds__(256) void combine_kernel(
    const float* __restrict__ Yh, const float* __restrict__ Yn,
    int fstart, int nfc, int t0c, int tcnt,
    float* __restrict__ sig, float* __restrict__ harm, float* __restrict__ noise)
{
    int idx = blockIdx.x * 256 + threadIdx.x;
    if (idx >= tcnt) return;
    const int b = blockIdx.y;
    const int t = t0c + idx;
    float hsum = 0.0f;
    const int fhi = (t + 509) / 240;
    #pragma unroll
    for (int q = 0; q < 6; q++) {
        int f = fhi - q;
        int j = t + 509 - 240 * f;
        if (f >= 0 && f < 1000 && j < 1261)
            hsum += Yh[((size_t)b * nfc + (f - fstart)) * 1280 + j];
    }
    float nsum = 0.0f;
    const int ghi = (t + 77) / 240;
    #pragma unroll
    for (int q = 0; q < 2; q++) {
        int f = ghi - q;
        int j = t + 77 - 240 * f;
        if (f >= 0 && f < 1000 && j < 397)
            nsum += Yn[((size_t)b * nfc + (f - fstart)) * 400 + j];
    }
    size_t o = (size_t)b * 240000 + t;
    harm[o]  = hsum;
    noise[o] = nsum;
    sig[o]   = hsum + nsum;
}

// ---------------------------------------------------------------------------
extern "C" void kernel_launch(void* const* d_in, const int* in_sizes, int n_in,
                              void* d_out, int out_size, void* d_ws, size_t ws_size,
                              hipStream_t stream)
{
    (void)in_sizes; (void)n_in; (void)out_size; (void)ws_size;
    const float* mel    = (const float*)d_in[0];
    const float* iphase = (const float*)d_in[1];
    const float* W_in   = (const float*)d_in[2];
    const float* b_in   = (const float*)d_in[3];
    const float* W1     = (const float*)d_in[4];
    const float* b1     = (const float*)d_in[5];
    const float* W2     = (const float*)d_in[6];
    const float* b2     = (const float*)d_in[7];
    const float* W_out  = (const float*)d_in[8];
    const float* b_out  = (const float*)d_in[9];
    float* ws = (float*)d_ws;

    // workspace layout (float offsets), peak 18,898,560 floats
    __hip_bfloat16* Chb = (__hip_bfloat16*)(ws + 0);        // [1024][512] bf16
    float*  Cn      = ws + 262144;                          // 12,640
    __hip_bfloat16* SPb = (__hip_bfloat16*)(ws + 274784);   // [8000][512] bf16
    float*  NP      = ws + 2322784;                         // 640,000
    float*  YhC     = ws + 0;                               // 2,621,440 (conv phase)
    float*  YnC     = ws + 2621440;                         // 819,200
    float*  f0w     = ws + 3440640;                         // 8,000
    double* base    = (double*)(ws + 3448640);              // 8,000 dbl
    float*  saw     = ws + 3472640;                         // 1,920,000
    float*  nz      = ws + 5392640;                         // 1,920,000
    float*  BA      = ws + 7312640;                         // 2,048,000 (h1,h3)
    float*  BB      = ws + 9360640;                         // 2,048,000 (h2)
    __hip_bfloat16* BAb = (__hip_bfloat16*)(ws + 11408640); // [8000][256] bf16
    __hip_bfloat16* WTb = (__hip_bfloat16*)(ws + 12432640); // [640][256] bf16
    float*  O       = ws + 12514560;                        // [8000][640]
    float*  IRh     = ws + 7312640;                         // [8000][1024] (aliases BA..O)
    float*  IRn     = ws + 17634560;                        // 1,264,000

    float* out       = (float*)d_out;
    float* sig_out   = out;
    float* f0_out    = out + 1920000;
    float* fph_out   = out + 1928000;
    float* harm_out  = out + 1928008;
    float* noise_out = out + 3848008;

    basis_h_bf16_t<<<1024, 256, 0, stream>>>(Chb);
    basis_kernel<80, 158><<<80, 256, 0, stream>>>(Cn);

    // MLP hidden layers in fp32 (f0-precision path); 3rd layer mirrors bf16
    gemm_kernel<0><<<dim3(125, 4), 256, 0, stream>>>(mel, W_in, b_in, nullptr, BA, nullptr, 8000, 256, 80);
    gemm_kernel<1><<<dim3(125, 4), 256, 0, stream>>>(BA,  W1,   b1,   BA,      BB, nullptr, 8000, 256, 256);
    gemm_kernel<1><<<dim3(125, 4), 256, 0, stream>>>(BB,  W2,   b2,   BB,      BA, BAb,     8000, 256, 256);

    // W_out: bf16 MFMA for SP/NP columns + exact fp32 GEMV (fused f0) for col 0
    convert_wout<<<640, 256, 0, stream>>>(W_out, WTb);
    mfma_gemm<256, 640><<<dim3(63, 5), 256, 0, stream>>>(
        (const unsigned short*)BAb, (const unsigned short*)WTb, O, 8000);
    f0_gemv<<<2000, 256, 0, stream>>>(BA, W_out, b_out, f0w, f0_out);

    transform2_kernel<<<(8000 * 592 + 255) / 256, 256, 0, stream>>>(O, b_out, SPb, NP);
    scan_par_kernel<<<8, 256, 0, stream>>>(f0w, iphase, base, fph_out);
    saw_noise_kernel<<<(1920000 + 255) / 256, 256, 0, stream>>>(f0w, base, iphase, saw, nz);

    // IR_h = SPb @ Chb^T  (bf16 MFMA, fp32 out, stride 1024)
    mfma_gemm<512, 1024><<<dim3(63, 8), 256, 0, stream>>>(
        (const unsigned short*)SPb, (const unsigned short*)Chb, IRh, 8000);
    // IR_n fp32
    gemm_kernel<2><<<dim3(125, 3), 256, 0, stream>>>(NP, Cn, nullptr, nullptr, IRn, nullptr, 8000, 158, 80);

    // chunked per-frame conv + overlap-add
    for (int c = 0; c < 4; c++) {
        int fs   = (c == 0) ? 0 : (250 * c - 3);
        int fe   = (c == 3) ? 1000 : (250 * (c + 1) + 3);
        int nfc  = fe - fs;
        int t0c  = 250 * 240 * c;
        int tcnt = 60000;
        frameconv_h<<<dim3((nfc + 3) / 4, 8), 320, 0, stream>>>(saw, IRh, YhC, fs, nfc);
        frameconv_n<<<dim3(nfc, 8), 128, 0, stream>>>(nz, IRn, YnC, fs, nfc);
        combine_kernel<<<dim3((tcnt + 255) / 256, 8), 256, 0, stream>>>(
            YhC, YnC, fs, nfc, t0c, tcnt, sig_out, harm_out, noise_out);
    }
}

// Round 6
// 314.697 us; speedup vs baseline: 2.9499x; 1.1147x over previous
//
#include <hip/hip_runtime.h>
#include <hip/hip_bf16.h>
#include <math.h>

#define TWO_PI_D 6.283185307179586476925286766559
#define TWO_PI_F 6.28318530718f

typedef short bf16x8 __attribute__((ext_vector_type(8)));
typedef float f32x4 __attribute__((ext_vector_type(4)));

// ---------------------------------------------------------------------------
// Harmonic basis, bf16, TRANSPOSED + padded: Ct[n][k], n<1024 (1022 valid), k<512
// ---------------------------------------------------------------------------
__global__ __launch_bounds__(256) void basis_h_bf16_t(__hip_bfloat16* __restrict__ Ct)
{
    const int n = blockIdx.x;            // 0..1023
    for (int k = threadIdx.x; k < 512; k += 256) {
        float v = 0.0f;
        if (n < 1022) {
            float hann = 0.5f * (1.0f - cosf(TWO_PI_F * (float)n / 1022.0f));
            float w = hann * (1.0f / 1022.0f);
            if (k == 0) v = w;
            else if (k == 511) v = (n & 1) ? w : -w;
            else {
                int m = (k * n) % 1022;
                float c = cosf(TWO_PI_F * (float)m / 1022.0f);
                v = 2.0f * w * ((k & 1) ? -c : c);
            }
        }
        Ct[(size_t)n * 512 + k] = __float2bfloat16(v);
    }
}

// noise basis, fp32: C[k][n], k<80, n<158
template<int NMAG, int NIR>
__global__ __launch_bounds__(256) void basis_kernel(float* __restrict__ C)
{
    const int k = blockIdx.x;
    for (int n = threadIdx.x; n < NIR; n += blockDim.x) {
        double hann = 0.5 * (1.0 - cos(TWO_PI_D * (double)n / (double)NIR));
        double w = hann / (double)NIR;
        double v;
        if (k == 0) v = w;
        else if (k == NMAG - 1) v = (n & 1) ? w : -w;
        else {
            long m = ((long)k * (long)n) % NIR;
            double c = cos(TWO_PI_D * (double)m / (double)NIR);
            v = 2.0 * w * ((k & 1) ? -c : c);
        }
        C[(size_t)k * NIR + n] = (float)v;
    }
}

// ---------------------------------------------------------------------------
// fp32 tiled GEMM 64x64x16 — precision path (MLP hidden layers + noise IR).
// ---------------------------------------------------------------------------
__device__ inline float gelu_f(float x) {
    float x3 = x * x * x;
    float t = tanhf(0.7978845608028654f * (x + 0.044715f * x3));
    return 0.5f * x * (1.0f + t);
}

template<int MODE>
__global__ __launch_bounds__(256) void gemm_kernel(
    const float* __restrict__ A, const float* __restrict__ Bm,
    const float* __restrict__ bias, const float* __restrict__ resid,
    float* __restrict__ C, __hip_bfloat16* __restrict__ Cb, int M, int N, int K)
{
    __shared__ float As[16][68];
    __shared__ float Bs[16][68];
    const int tid = threadIdx.x;
    const int tx = tid & 15, ty = tid >> 4;
    const int m0 = blockIdx.x * 64;
    const int n0 = blockIdx.y * 64;
    const int ar  = tid >> 2;
    const int ac4 = (tid & 3) << 2;
    const int bk  = tid >> 4;
    const int bn4 = (tid & 15) << 2;
    float acc[4][4] = {};
    for (int k0 = 0; k0 < K; k0 += 16) {
        float4 av = *(const float4*)(A + (size_t)(m0 + ar) * K + k0 + ac4);
        As[ac4 + 0][ar] = av.x;
        As[ac4 + 1][ar] = av.y;
        As[ac4 + 2][ar] = av.z;
        As[ac4 + 3][ar] = av.w;
        const float* Bp = Bm + (size_t)(k0 + bk) * N + n0 + bn4;
        #pragma unroll
        for (int i = 0; i < 4; i++)
            Bs[bk][bn4 + i] = (n0 + bn4 + i < N) ? Bp[i] : 0.0f;
        __syncthreads();
        #pragma unroll
        for (int kk = 0; kk < 16; kk++) {
            float4 a4 = *(const float4*)&As[kk][ty << 2];
            float4 b4 = *(const float4*)&Bs[kk][tx << 2];
            float a[4] = {a4.x, a4.y, a4.z, a4.w};
            float b[4] = {b4.x, b4.y, b4.z, b4.w};
            #pragma unroll
            for (int i = 0; i < 4; i++)
                #pragma unroll
                for (int j = 0; j < 4; j++)
                    acc[i][j] = fmaf(a[i], b[j], acc[i][j]);
        }
        __syncthreads();
    }
    #pragma unroll
    for (int i = 0; i < 4; i++) {
        int m = m0 + (ty << 2) + i;
        #pragma unroll
        for (int j = 0; j < 4; j++) {
            int n = n0 + (tx << 2) + j;
            if (n < N) {
                float v = acc[i][j];
                if (bias) v += bias[n];
                if (MODE == 0) v = tanhf(v);
                else if (MODE == 1) v = resid[(size_t)m * N + n] + gelu_f(v);
                C[(size_t)m * N + n] = v;
                if (MODE == 1 && Cb) Cb[(size_t)m * N + n] = __float2bfloat16(v);
            }
        }
    }
}

// ---------------------------------------------------------------------------
// bf16 MFMA GEMM: A [M][K] bf16, Bt [NPAD][K] bf16, C [M][NSTRIDE] fp32
// ---------------------------------------------------------------------------
template<int K, int NSTRIDE>
__global__ __launch_bounds__(256) void mfma_gemm(
    const unsigned short* __restrict__ A, const unsigned short* __restrict__ Bt,
    float* __restrict__ C, int M)
{
    __shared__ __align__(16) unsigned short As[128][72];
    __shared__ __align__(16) unsigned short Bs[128][72];
    const int tid = threadIdx.x;
    const int m0 = blockIdx.x * 128;
    const int n0 = blockIdx.y * 128;
    const int wid = tid >> 6;
    const int lane = tid & 63;
    const int wm = (wid >> 1) << 6;
    const int wn = (wid & 1) << 6;

    f32x4 acc[4][4];
    #pragma unroll
    for (int i = 0; i < 4; i++)
        #pragma unroll
        for (int j = 0; j < 4; j++)
            acc[i][j] = (f32x4){0.f, 0.f, 0.f, 0.f};

    for (int k0 = 0; k0 < K; k0 += 64) {
        #pragma unroll
        for (int s = 0; s < 4; s++) {
            int g = tid + (s << 8);
            int row = g >> 3;
            int kc = (g & 7) << 3;
            int ra = m0 + row; if (ra > M - 1) ra = M - 1;
            *(uint4*)&As[row][kc] = *(const uint4*)&A[(size_t)ra * K + k0 + kc];
            *(uint4*)&Bs[row][kc] = *(const uint4*)&Bt[(size_t)(n0 + row) * K + k0 + kc];
        }
        __syncthreads();
        #pragma unroll
        for (int kk = 0; kk < 64; kk += 32) {
            bf16x8 av[4], bv[4];
            const int koff = kk + ((lane >> 4) << 3);
            #pragma unroll
            for (int mt = 0; mt < 4; mt++)
                av[mt] = *(const bf16x8*)&As[wm + (mt << 4) + (lane & 15)][koff];
            #pragma unroll
            for (int nt = 0; nt < 4; nt++)
                bv[nt] = *(const bf16x8*)&Bs[wn + (nt << 4) + (lane & 15)][koff];
            #pragma unroll
            for (int mt = 0; mt < 4; mt++)
                #pragma unroll
                for (int nt = 0; nt < 4; nt++)
                    acc[mt][nt] = __builtin_amdgcn_mfma_f32_16x16x32_bf16(
                        av[mt], bv[nt], acc[mt][nt], 0, 0, 0);
        }
        __syncthreads();
    }
    const int cr0 = m0 + wm + ((lane >> 4) << 2);
    const int cc0 = n0 + wn + (lane & 15);
    #pragma unroll
    for (int mt = 0; mt < 4; mt++)
        #pragma unroll
        for (int nt = 0; nt < 4; nt++)
            #pragma unroll
            for (int j = 0; j < 4; j++) {
                int r = cr0 + (mt << 4) + j;
                if (r < M) C[(size_t)r * NSTRIDE + cc0 + (nt << 4)] = acc[mt][nt][j];
            }
}

// ---------------------------------------------------------------------------
__global__ __launch_bounds__(256) void convert_wout(
    const float* __restrict__ W, __hip_bfloat16* __restrict__ WTb)
{
    const int n = blockIdx.x;           // 0..639
    const int k = threadIdx.x;          // 0..255
    float v = (n < 593) ? W[(size_t)k * 593 + n] : 0.0f;
    WTb[(size_t)n * 256 + k] = __float2bfloat16(v);
}

// exact-fp32 f0 logit + fused precise f0 transform
__global__ __launch_bounds__(256) void f0_gemv(
    const float* __restrict__ h3, const float* __restrict__ Wout,
    const float* __restrict__ b_out, float* __restrict__ f0w, float* __restrict__ f0out)
{
    const int row = blockIdx.x * 4 + (threadIdx.x >> 6);
    const int lane = threadIdx.x & 63;
    const float* a = h3 + (size_t)row * 256;
    float s = 0.0f;
    #pragma unroll
    for (int q = 0; q < 4; q++) {
        int k = lane + (q << 6);
        s = fmaf(a[k], Wout[(size_t)k * 593], s);
    }
    #pragma unroll
    for (int off = 32; off; off >>= 1) s += __shfl_down(s, off, 64);
    if (lane == 0) {
        float lg = s + b_out[0];
        float sg = 1.0f / (1.0f + expf(-lg));
        float f0 = 80.0f * powf(12.5f, sg);
        if (f0 < 80.0f) f0 = 0.0f;
        f0w[row] = f0;
        f0out[row] = f0;
    }
}

// ---------------------------------------------------------------------------
// SP/NP from O[8000][640] cols 1..592 (+bias), fast-math exp_sigmoid
// ---------------------------------------------------------------------------
__global__ __launch_bounds__(256) void transform2_kernel(
    const float* __restrict__ O, const float* __restrict__ b_out,
    __hip_bfloat16* __restrict__ SPb, float* __restrict__ NP)
{
    int idx = blockIdx.x * 256 + threadIdx.x;
    if (idx >= 8000 * 592) return;
    int row = idx / 592;
    int c = idx - row * 592 + 1;
    float v = O[(size_t)row * 640 + c] + b_out[c];
    float s = 1.0f / (1.0f + __expf(-v));
    float p = 2.0f * __powf(s, 2.3025851f) + 1e-7f;
    if (c < 513) SPb[(size_t)row * 512 + (c - 1)] = __float2bfloat16(p);
    else         NP[(size_t)row * 80 + (c - 513)] = p;
}

// ---------------------------------------------------------------------------
// Parallel fp64 frame-level pitch scan
// ---------------------------------------------------------------------------
__device__ inline double shfl_up_d(double x, int off) {
    long long l = __double_as_longlong(x);
    int lo = (int)(l & 0xffffffffLL);
    int hi = (int)(l >> 32);
    lo = __shfl_up(lo, off, 64);
    hi = __shfl_up(hi, off, 64);
    return __longlong_as_double(((long long)hi << 32) | (unsigned int)lo);
}

__global__ __launch_bounds__(256) void scan_par_kernel(
    const float* __restrict__ f0w, const float* __restrict__ iphase,
    double* __restrict__ base, float* __restrict__ fph)
{
    __shared__ double wsum[4];
    const int b = blockIdx.x;
    const int tid = threadIdx.x;
    const int lane = tid & 63;
    const float* f0 = f0w + b * 1000;
    double s[4];
    double loc = 0.0;
    #pragma unroll
    for (int q = 0; q < 4; q++) {
        int f = tid * 4 + q;
        s[q] = loc;
        if (f < 1000) {
            double c  = (double)f0[f];
            double nx = (double)f0[(f < 999) ? (f + 1) : 999];
            loc += 120.5 * c + 119.5 * nx;
        }
    }
    double v = loc;
    #pragma unroll
    for (int off = 1; off < 64; off <<= 1) {
        double o = shfl_up_d(v, off);
        if (lane >= off) v += o;
    }
    if (lane == 63) wsum[tid >> 6] = v;
    __syncthreads();
    double wpre = 0.0;
    const int w = tid >> 6;
    for (int i = 0; i < w; i++) wpre += wsum[i];
    const double excl = wpre + v - loc;
    #pragma unroll
    for (int q = 0; q < 4; q++) {
        int f = tid * 4 + q;
        if (f < 1000) base[b * 1000 + f] = excl + s[q];
    }
    if (tid == 255) {
        double total = excl + loc;
        double u  = total * (1.0 / 24000.0);
        double ph = TWO_PI_D * u + (double)iphase[b];
        fph[b] = (float)fmod(ph, TWO_PI_D);
    }
}

// ---------------------------------------------------------------------------
// Sawtooth (fp64 phase) + threefry2x32 noise (bit-exact)
// ---------------------------------------------------------------------------
__device__ inline unsigned rotl32(unsigned x, int d) { return (x << d) | (x >> (32 - d)); }

__global__ __launch_bounds__(256) void saw_noise_kernel(
    const float* __restrict__ f0w, const double* __restrict__ base,
    const float* __restrict__ iphase, float* __restrict__ saw, float* __restrict__ nz)
{
    int idx = blockIdx.x * 256 + threadIdx.x;
    if (idx >= 8 * 240000) return;
    int b = idx / 240000;
    int t = idx - b * 240000;
    int f = t / 240;
    int r = t - f * 240;
    double c  = (double)f0w[b * 1000 + f];
    double nx = (double)f0w[b * 1000 + ((f < 999) ? (f + 1) : 999)];
    double rr = (double)r;
    double Bc = rr * (rr + 1.0) * (1.0 / 480.0);
    double Ac = (rr + 1.0) - Bc;
    double cum = base[b * 1000 + f] + Ac * c + Bc * nx;
    double u  = cum * (1.0 / 24000.0) + (double)iphase[b] * (1.0 / TWO_PI_D);
    double fr = u - floor(u);
    saw[idx] = (float)(2.0 * fr - 1.0);

    const unsigned n2 = 960000u;
    unsigned mi = (unsigned)idx;
    unsigned i0 = (mi < n2) ? mi : (mi - n2);
    unsigned x0 = i0, x1 = i0 + n2;
    const unsigned ks0 = 0u, ks1 = 123u, ks2 = 0x1BD11BDAu ^ 0u ^ 123u;
    x0 += ks0; x1 += ks1;
#define TF_R(rot) { x0 += x1; x1 = rotl32(x1, rot); x1 ^= x0; }
    TF_R(13) TF_R(15) TF_R(26) TF_R(6)
    x0 += ks1; x1 += ks2 + 1u;
    TF_R(17) TF_R(29) TF_R(16) TF_R(24)
    x0 += ks2; x1 += ks0 + 2u;
    TF_R(13) TF_R(15) TF_R(26) TF_R(6)
    x0 += ks0; x1 += ks1 + 3u;
    TF_R(17) TF_R(29) TF_R(16) TF_R(24)
    x0 += ks1; x1 += ks2 + 4u;
    TF_R(13) TF_R(15) TF_R(26) TF_R(6)
    x0 += ks2; x1 += ks0 + 5u;
#undef TF_R
    unsigned bits = (mi < n2) ? x0 : x1;
    float uf = __uint_as_float((bits >> 9) | 0x3f800000u) - 1.0f;
    nz[idx] = uf * 2.0f - 1.0f;
}

// ---------------------------------------------------------------------------
// Per-frame conv, harmonic. 4 frames/block, 80 thr/frame, 16 outputs/thread.
// Circular 5xfloat4 window (full period-5 unroll, no register shifts) +
// XOR chunk swizzle on the w LDS array (kills the 8-way bank conflict of
// the 64B j0 stride).
// ---------------------------------------------------------------------------
__device__ inline int swz(int a) {
    int c = a >> 2;
    c ^= (((c >> 3) & 1) << 1) | ((c >> 4) & 1);
    return (c << 2) | (a & 3);
}

__global__ __launch_bounds__(320) void frameconv_h(
    const float* __restrict__ audio, const float* __restrict__ IR,
    float* __restrict__ Y)
{
    // frame-local w layout (logical word a): [0,248) zeros (8 slack + 240),
    // [248,1270) IR, [1270,1608) zeros. Physical index = swz(a), frame
    // stride 1624 words (banks offset 0/24/16/8 across the 4 frames).
    __shared__ __align__(16) float u_s[4][240];
    __shared__ __align__(16) float w_raw[4][1624];
    const int fl0 = blockIdx.x * 4;
    const int b = blockIdx.y;
    const int tid = threadIdx.x;

    for (int i = tid; i < 4 * 586; i += 320) {
        int fr = i / 586, r = i - fr * 586;
        int a = (r < 248) ? r : (1270 + r - 248);
        w_raw[fr][swz(a)] = 0.0f;
    }
    for (int i = tid; i < 4 * 1022; i += 320) {
        int fr = i / 1022, d = i - fr * 1022;
        w_raw[fr][swz(248 + d)] = IR[((size_t)b * 1000 + fl0 + fr) * 1024 + d];
    }
    for (int i = tid; i < 4 * 240; i += 320) {
        int fr = i / 240, r = i - fr * 240;
        u_s[fr][r] = audio[(size_t)b * 240000 + (size_t)(fl0 + fr) * 240 + r];
    }
    __syncthreads();

    const int fr = tid & 3;
    const int j0 = (tid >> 2) << 4;      // 0,16,...,1264
    const float* uf = u_s[fr];
    const float* wfr = w_raw[fr];
    float acc[16];
    #pragma unroll
    for (int q = 0; q < 16; q++) acc[q] = 0.0f;

    // C holds 5 float4 chunks; slot s of chunk (q_cur + d) = ((d - p) mod 5)
    float C[20];
    const int B0 = 248 + j0;             // frame-local word of output j0's top tap
    #pragma unroll
    for (int d = -1; d < 4; d++)
        *(float4*)&C[4 * ((d + 5) % 5)] = *(const float4*)&wfr[swz(B0 + 4 * d)];

    #pragma unroll 1
    for (int M = 0; M < 12; M++) {
        const int iBase = 20 * M;
        #pragma unroll
        for (int p = 0; p < 5; p++) {
            float4 u4 = *(const float4*)&uf[iBase + 4 * p];
            float uu[4] = {u4.x, u4.y, u4.z, u4.w};
            #pragma unroll
            for (int q = 0; q < 16; q++)
                #pragma unroll
                for (int k = 0; k < 4; k++) {
                    const int dd = (q - k) >> 2;             // -1..3
                    const int s  = ((dd - p) % 5 + 5) % 5;
                    acc[q] = fmaf(uu[k], C[4 * s + ((q - k) & 3)], acc[q]);
                }
            // evict chunk q_cur+3, load chunk q_cur-2 (word B0-8-4*(5M+p))
            *(float4*)&C[4 * (((3 - p) % 5 + 5) % 5)] =
                *(const float4*)&wfr[swz(B0 - 8 - iBase - 4 * p)];
        }
    }

    float* yp = &Y[((size_t)b * 1000 + fl0 + fr) * 1280 + j0];
    #pragma unroll
    for (int cc = 0; cc < 4; cc++) {
        float4 r4 = {acc[4*cc], acc[4*cc+1], acc[4*cc+2], acc[4*cc+3]};
        *(float4*)&yp[4*cc] = r4;
    }
}

// ---------------------------------------------------------------------------
// Per-frame conv, noise: iterate IR, window over audio.
// ---------------------------------------------------------------------------
#define CONV_GROUP(u4) \
    a0 = fmaf(u4.x, Whi.x, a0); a1 = fmaf(u4.x, Whi.y, a1); a2 = fmaf(u4.x, Whi.z, a2); a3 = fmaf(u4.x, Whi.w, a3); \
    a0 = fmaf(u4.y, Wlo.w, a0); a1 = fmaf(u4.y, Whi.x, a1); a2 = fmaf(u4.y, Whi.y, a2); a3 = fmaf(u4.y, Whi.z, a3); \
    a0 = fmaf(u4.z, Wlo.z, a0); a1 = fmaf(u4.z, Wlo.w, a1); a2 = fmaf(u4.z, Whi.x, a2); a3 = fmaf(u4.z, Whi.y, a3); \
    a0 = fmaf(u4.w, Wlo.y, a0); a1 = fmaf(u4.w, Wlo.z, a1); a2 = fmaf(u4.w, Wlo.w, a2); a3 = fmaf(u4.w, Whi.x, a3);

__global__ __launch_bounds__(128) void frameconv_n(
    const float* __restrict__ audio, const float* __restrict__ IR,
    float* __restrict__ Y)
{
    __shared__ __align__(16) float u_s[160];
    __shared__ __align__(16) float w_s[560];
    const int f = blockIdx.x;
    const int b = blockIdx.y;
    const int tid = threadIdx.x;
    const float* irow = IR + ((size_t)b * 1000 + f) * 158;
    for (int i = tid; i < 160; i += 128) {
        u_s[i] = (i < 158) ? irow[i] : 0.0f;
        w_s[i] = 0.0f;
        w_s[400 + i] = 0.0f;
    }
    for (int i = tid; i < 240; i += 128)
        w_s[160 + i] = audio[(size_t)b * 240000 + (size_t)f * 240 + i];
    __syncthreads();

    const int j0 = tid << 2;
    if (j0 >= 400) return;
    int base = 160 + j0 - 4;
    float4 Wlo = *(const float4*)&w_s[base];
    float4 Whi = *(const float4*)&w_s[base + 4];
    float a0 = 0.f, a1 = 0.f, a2 = 0.f, a3 = 0.f;
    #pragma unroll 4
    for (int t = 0; t < 156; t += 4) {
        float4 u4 = *(const float4*)&u_s[t];
        CONV_GROUP(u4)
        Whi = Wlo;
        base -= 4;
        Wlo = *(const float4*)&w_s[base];
    }
    {
        float4 u4 = *(const float4*)&u_s[156];
        CONV_GROUP(u4)
    }
    float4 r; r.x = a0; r.y = a1; r.z = a2; r.w = a3;
    *(float4*)&Y[((size_t)b * 1000 + f) * 400 + j0] = r;
}

// ---------------------------------------------------------------------------
// Overlap-add + 'same' slice + outputs (full range, single launch)
// ---------------------------------------------------------------------------
__global__ __launch_bounds__(256) void combine_kernel(
    const float* __restrict__ Yh, const float* __restrict__ Yn,
    float* __restrict__ sig, float* __restrict__ harm, float* __restrict__ noise)
{
    int t = blockIdx.x * 256 + threadIdx.x;
    if (t >= 240000) return;
    const int b = blockIdx.y;
    float hsum = 0.0f;
    const int fhi = (t + 509) / 240;
    #pragma unroll
    for (int q = 0; q < 6; q++) {
        int f = fhi - q;
        int j = t + 509 - 240 * f;
        if (f >= 0 && f < 1000 && j < 1261)
            hsum += Yh[((size_t)b * 1000 + f) * 1280 + j];
    }
    float nsum = 0.0f;
    const int ghi = (t + 77) / 240;
    #pragma unroll
    for (int q = 0; q < 2; q++) {
        int f = ghi - q;
        int j = t + 77 - 240 * f;
        if (f >= 0 && f < 1000 && j < 397)
            nsum += Yn[((size_t)b * 1000 + f) * 400 + j];
    }
    size_t o = (size_t)b * 240000 + t;
    harm[o]  = hsum;
    noise[o] = nsum;
    sig[o]   = hsum + nsum;
}

// ---------------------------------------------------------------------------
extern "C" void kernel_launch(void* const* d_in, const int* in_sizes, int n_in,
                              void* d_out, int out_size, void* d_ws, size_t ws_size,
                              hipStream_t stream)
{
    (void)in_sizes; (void)n_in; (void)out_size; (void)ws_size;
    const float* mel    = (const float*)d_in[0];
    const float* iphase = (const float*)d_in[1];
    const float* W_in   = (const float*)d_in[2];
    const float* b_in   = (const float*)d_in[3];
    const float* W1     = (const float*)d_in[4];
    const float* b1     = (const float*)d_in[5];
    const float* W2     = (const float*)d_in[6];
    const float* b2     = (const float*)d_in[7];
    const float* W_out  = (const float*)d_in[8];
    const float* b_out  = (const float*)d_in[9];
    float* ws = (float*)d_ws;

    // workspace layout (float offsets), peak 32,338,560 floats = 129.4 MB
    // (ws_size ~268 MB per harness fill)
    __hip_bfloat16* Chb = (__hip_bfloat16*)(ws + 0);        // [1024][512] bf16
    float*  Cn      = ws + 262144;                          // 12,640
    __hip_bfloat16* SPb = (__hip_bfloat16*)(ws + 274784);   // [8000][512] bf16
    float*  NP      = ws + 2322784;                         // 640,000
    float*  f0w     = ws + 3440640;                         // 8,000
    double* base    = (double*)(ws + 3448640);              // 8,000 dbl
    float*  saw     = ws + 3472640;                         // 1,920,000
    float*  nz      = ws + 5392640;                         // 1,920,000
    float*  BA      = ws + 7312640;                         // 2,048,000 (h1,h3)
    float*  BB      = ws + 9360640;                         // 2,048,000 (h2)
    __hip_bfloat16* BAb = (__hip_bfloat16*)(ws + 11408640); // [8000][256] bf16
    __hip_bfloat16* WTb = (__hip_bfloat16*)(ws + 12432640); // [640][256] bf16
    float*  O       = ws + 12514560;                        // [8000][640]
    float*  IRh     = ws + 7312640;                         // [8000][1024] (aliases BA..O, dead then)
    float*  IRn     = ws + 17634560;                        // 1,264,000
    float*  YhF     = ws + 18898560;                        // [8][1000][1280] = 10,240,000
    float*  YnF     = ws + 29138560;                        // [8][1000][400]  =  3,200,000

    float* out       = (float*)d_out;
    float* sig_out   = out;
    float* f0_out    = out + 1920000;
    float* fph_out   = out + 1928000;
    float* harm_out  = out + 1928008;
    float* noise_out = out + 3848008;

    basis_h_bf16_t<<<1024, 256, 0, stream>>>(Chb);
    basis_kernel<80, 158><<<80, 256, 0, stream>>>(Cn);

    // MLP hidden layers in fp32 (f0-precision path); 3rd layer mirrors bf16
    gemm_kernel<0><<<dim3(125, 4), 256, 0, stream>>>(mel, W_in, b_in, nullptr, BA, nullptr, 8000, 256, 80);
    gemm_kernel<1><<<dim3(125, 4), 256, 0, stream>>>(BA,  W1,   b1,   BA,      BB, nullptr, 8000, 256, 256);
    gemm_kernel<1><<<dim3(125, 4), 256, 0, stream>>>(BB,  W2,   b2,   BB,      BA, BAb,     8000, 256, 256);

    // W_out: bf16 MFMA for SP/NP columns + exact fp32 GEMV (fused f0) for col 0
    convert_wout<<<640, 256, 0, stream>>>(W_out, WTb);
    mfma_gemm<256, 640><<<dim3(63, 5), 256, 0, stream>>>(
        (const unsigned short*)BAb, (const unsigned short*)WTb, O, 8000);
    f0_gemv<<<2000, 256, 0, stream>>>(BA, W_out, b_out, f0w, f0_out);

    transform2_kernel<<<(8000 * 592 + 255) / 256, 256, 0, stream>>>(O, b_out, SPb, NP);
    scan_par_kernel<<<8, 256, 0, stream>>>(f0w, iphase, base, fph_out);
    saw_noise_kernel<<<(1920000 + 255) / 256, 256, 0, stream>>>(f0w, base, iphase, saw, nz);

    // IR_h = SPb @ Chb^T  (bf16 MFMA, fp32 out, stride 1024)
    mfma_gemm<512, 1024><<<dim3(63, 8), 256, 0, stream>>>(
        (const unsigned short*)SPb, (const unsigned short*)Chb, IRh, 8000);
    // IR_n fp32
    gemm_kernel<2><<<dim3(125, 3), 256, 0, stream>>>(NP, Cn, nullptr, nullptr, IRn, nullptr, 8000, 158, 80);

    // per-frame conv + overlap-add (single pass, no chunking)
    frameconv_h<<<dim3(250, 8), 320, 0, stream>>>(saw, IRh, YhF);
    frameconv_n<<<dim3(1000, 8), 128, 0, stream>>>(nz, IRn, YnF);
    combine_kernel<<<dim3(938, 8), 256, 0, stream>>>(YhF, YnF, sig_out, harm_out, noise_out);
}